// Round 15
// baseline (472.446 us; speedup 1.0000x reference)
//
#include <hip/hip_runtime.h>

#define NN 50000
#define NE 600000
#define SREP 64

typedef __attribute__((ext_vector_type(8))) short short8;
typedef __attribute__((ext_vector_type(4))) float f32x4;
typedef __attribute__((ext_vector_type(4))) unsigned uint4v;
typedef __attribute__((ext_vector_type(4))) int int4v;

__device__ __forceinline__ float bf2f(unsigned short u){
  union { unsigned int i; float f; } c; c.i = ((unsigned int)u) << 16; return c.f;
}
__device__ __forceinline__ float lof(unsigned v){
  union { unsigned int i; float f; } c; c.i = v << 16; return c.f;
}
__device__ __forceinline__ float hif(unsigned v){
  union { unsigned int i; float f; } c; c.i = v & 0xFFFF0000u; return c.f;
}
__device__ __forceinline__ unsigned short f2b(float f){
  union { float f; unsigned int i; } c; c.f = f;
  unsigned int i = c.i;
  return (unsigned short)((i + 0x7FFFu + ((i >> 16) & 1u)) >> 16);
}

// ---------- fast workspace zero ----------
__global__ __launch_bounds__(256) void k_zero(uint4v* __restrict__ p, int n4){
  int i = blockIdx.x*256 + threadIdx.x;
  if (i < n4) p[i] = (uint4v){0,0,0,0};
}

// ---------- per-block BN coefficient computation from replicated stats ----------
template<int N>
__device__ __forceinline__ void compute_ab(const float* __restrict__ st,
    const float* __restrict__ gam, const float* __restrict__ bet, float2* absh){
  int tid = threadIdx.x;
  if (tid < N){
    float s = 0.f, q = 0.f;
    #pragma unroll 16
    for (int r = 0; r < SREP; ++r){
      s += st[r*2*N + tid];
      q += st[r*2*N + N + tid];
    }
    float mu = s * (1.f/(float)NN);
    float var = fmaxf(q * (1.f/(float)NN) - mu*mu, 0.f);
    float a = gam[tid] * rsqrtf(var + 1e-5f);
    absh[tid] = make_float2(a, bet[tid] - mu*a);
  }
}

// ---------- fused preprocessing: cvt | hist | wconv | zero dummy rows ----------
struct W6 { const float* w[6]; unsigned short* o[6]; };
__global__ __launch_bounds__(256) void k_pre(const float* __restrict__ features,
    unsigned short* __restrict__ H0, unsigned short* __restrict__ Hp,
    const int* __restrict__ dst, int* __restrict__ deg, W6 jb){
  int b = blockIdx.x, tid = threadIdx.x;
  if (b < 6250){                       // cvt: NN*128 floats as float4 -> bf16x4
    int i = b*256 + tid;               // i < NN*32 exactly
    float4 v = ((const float4*)features)[i];
    uint2 o;
    o.x = (unsigned)f2b(v.x) | ((unsigned)f2b(v.y) << 16);
    o.y = (unsigned)f2b(v.z) | ((unsigned)f2b(v.w) << 16);
    ((uint2*)H0)[i] = o;
  } else if (b < 6250 + 2344){         // hist
    int i = (b - 6250)*256 + tid;
    if (i < NE) atomicAdd(&deg[dst[i]], 1);
  } else if (b < 6250 + 2344 + 304){   // weight transpose+convert, 6 jobs
    int i = (b - 8594)*256 + tid;
    if (i < 77824){
      int job, base, K, N;
      if (i < 65536){ job = i >> 14; base = job << 14; K = 128; N = 128; }
      else if (i < 73728){ job = 4; base = 65536; K = 128; N = 64; }
      else { job = 5; base = 73728; K = 64; N = 64; }
      int t = i - base;
      int k = t & (K-1);
      int n = t / K;
      jb.o[job][t] = f2b(jb.w[job][k*N + n]);
    }
  } else {                             // zero dummy row NN of both gather tables
    if (tid < 32){
      unsigned short* bp = (tid < 16) ? H0 : Hp;
      ((uint4v*)bp)[(size_t)NN*16 + (tid & 15)] = (uint4v){0,0,0,0};
    }
  }
}

// ---------- CSR offsets (block-local scan over PADDED degrees + pad-slot fill) ----------
__global__ void k_offsets(const int* __restrict__ deg, int* __restrict__ row_off,
                          int* __restrict__ cur, int* __restrict__ col,
                          int* __restrict__ total){
  __shared__ int ws[4];
  __shared__ int wbase[4];
  int tid = threadIdx.x, lane = tid & 63, wid = tid >> 6;
  int i = blockIdx.x*256 + tid;
  int v = (i < NN) ? deg[i] : 0;
  int vp = (v + 3) & ~3;               // padded degree
  int x = vp;
  #pragma unroll
  for (int o = 1; o < 64; o <<= 1){
    int t = __shfl_up(x, o);
    if (lane >= o) x += t;
  }
  if (lane == 63) ws[wid] = x;
  __syncthreads();
  if (tid == 0){
    int s0 = ws[0], s1 = ws[1], s2 = ws[2], s3 = ws[3];
    int b = atomicAdd(total, s0+s1+s2+s3);
    wbase[0] = b; wbase[1] = b+s0; wbase[2] = b+s0+s1; wbase[3] = b+s0+s1+s2;
  }
  __syncthreads();
  if (i < NN){
    int excl = wbase[wid] + x - vp;
    row_off[i] = excl;
    cur[i] = excl;
    for (int t = v; t < vp; ++t) col[excl + t] = NN;   // pad -> zero dummy node
  }
}

__global__ void k_fill(const int* __restrict__ src, const int* __restrict__ dst,
                       int* __restrict__ cur, int* __restrict__ col, int e){
  int i = blockIdx.x*blockDim.x + threadIdx.x;
  if (i >= e) return;
  int d = dst[i];
  int pos = atomicAdd(&cur[d], 1);
  col[pos] = src[i];
}

// ---------- aggregation (XCD-chunked, PURE ADD): x = h + mean(h[neigh]) ----------
// Block b: column chunk = b&7 (16 cols = 32B of the 256B row), node group b>>3.
// blockIdx round-robins over the 8 XCDs -> all blocks for one chunk share one
// XCD, whose table working set is 50000 rows x 64B lines = 3.2MB -> L2-resident.
// One node per THREAD: every gather instruction has 64 independent rows in
// flight; col indices load as int4 (row_off is 4-aligned by padding). Slots
// beyond a node's padded degree select the zero dummy row (adds 0). Loop bound
// is the wave-max padded degree. col/X use non-temporal hints to protect the
// table's L2 residency. col[] has +4096 ints slack for the pre-select loads.
__global__ __launch_bounds__(256) void k_agg(const unsigned short* __restrict__ T,
    const int* __restrict__ row_off, const int* __restrict__ deg,
    const int* __restrict__ col, unsigned short* __restrict__ X){
  int tid = threadIdx.x;
  int chunk = blockIdx.x & 7;
  int u = (int)(blockIdx.x >> 3)*256 + tid;
  bool valid = (u < NN);
  int node = valid ? u : NN;
  int beg = valid ? row_off[u] : 0;    // multiple of 4
  int d   = valid ? deg[u] : 0;
  int dp  = (d + 3) & ~3;
  int m = dp;
  #pragma unroll
  for (int o = 1; o < 64; o <<= 1) m = max(m, __shfl_xor(m, o));
  const uint4v* tp = (const uint4v*)T;           // 16 uint4v per row
  size_t co = (size_t)chunk*2;
  uint4v h0 = tp[(size_t)node*16 + co];
  uint4v h1 = tp[(size_t)node*16 + co + 1];
  float s[16];
  #pragma unroll
  for (int i = 0; i < 16; ++i) s[i] = 0.f;
  auto ACC8 = [&](uint4v v, int o){
    s[o+0] += lof(v.x); s[o+1] += hif(v.x);
    s[o+2] += lof(v.y); s[o+3] += hif(v.y);
    s[o+4] += lof(v.z); s[o+5] += hif(v.z);
    s[o+6] += lof(v.w); s[o+7] += hif(v.w);
  };
  const int4v* colv = (const int4v*)(col + beg);
  for (int e0 = 0; e0 < m; e0 += 4){
    int4v c4 = __builtin_nontemporal_load(colv + (e0 >> 2));
    int idx[4];
    idx[0] = (e0     < dp) ? c4.x : NN;
    idx[1] = (e0 + 1 < dp) ? c4.y : NN;
    idx[2] = (e0 + 2 < dp) ? c4.z : NN;
    idx[3] = (e0 + 3 < dp) ? c4.w : NN;
    uint4v v0[4], v1[4];
    #pragma unroll
    for (int uu = 0; uu < 4; ++uu){
      v0[uu] = tp[(size_t)idx[uu]*16 + co];
      v1[uu] = tp[(size_t)idx[uu]*16 + co + 1];
    }
    #pragma unroll
    for (int uu = 0; uu < 4; ++uu){ ACC8(v0[uu], 0); ACC8(v1[uu], 8); }
  }
  if (valid){
    float inv = 1.f / (float)(d > 0 ? d : 1);
    float hf[16] = {lof(h0.x),hif(h0.x),lof(h0.y),hif(h0.y),
                    lof(h0.z),hif(h0.z),lof(h0.w),hif(h0.w),
                    lof(h1.x),hif(h1.x),lof(h1.y),hif(h1.y),
                    lof(h1.z),hif(h1.z),lof(h1.w),hif(h1.w)};
    unsigned w[8];
    #pragma unroll
    for (int i = 0; i < 8; ++i){
      float x0 = hf[2*i]   + s[2*i]*inv;
      float x1 = hf[2*i+1] + s[2*i+1]*inv;
      w[i] = (unsigned)f2b(x0) | ((unsigned)f2b(x1) << 16);
    }
    uint4v o0 = {w[0], w[1], w[2], w[3]};
    uint4v o1 = {w[4], w[5], w[6], w[7]};
    __builtin_nontemporal_store(o0, (uint4v*)X + (size_t)u*16 + co);
    __builtin_nontemporal_store(o1, (uint4v*)X + (size_t)u*16 + co + 1);
  }
}

// ---------- GEMM: 512-thread blocks, column-split; B panel per wave in regs ----------
// Y[NN][N] = act(A)[NN][K] @ BT[N][K]^T, fused BN stats; APPLY = BN+relu on A-load
template<int KSTEPS, int NT, int CS, bool APPLY>
__global__ __launch_bounds__(512) void k_gemm(const unsigned short* __restrict__ A,
    const unsigned short* __restrict__ BT,
    const float* __restrict__ stIn, const float* __restrict__ gam,
    const float* __restrict__ bet,
    unsigned short* __restrict__ Y, float* __restrict__ statsAcc){
  constexpr int K = KSTEPS*32;
  constexpr int N = CS*NT*16;
  constexpr int TILES = NN/16;         // 3125
  constexpr int TPB = (CS==2) ? 4 : 8;
  __shared__ float red[2*N];
  __shared__ float2 absh[K];
  if (APPLY) compute_ab<K>(stIn, gam, bet, absh);
  int tid = threadIdx.x;
  int lane = tid & 63, w = tid >> 6;
  int r = lane & 15, g = lane >> 4;
  int tile = blockIdx.x*TPB + ((CS==2) ? (w & 3) : w);
  int ch = (CS==2) ? (w >> 2) : 0;
  bool valid = (tile < TILES);
  int arow = valid ? tile*16 + r : 0;
  short8 af[KSTEPS];
  #pragma unroll
  for (int kk = 0; kk < KSTEPS; ++kk)
    af[kk] = *(const short8*)(A + (size_t)arow*K + kk*32 + g*8);
  short8 bf[KSTEPS][NT];
  #pragma unroll
  for (int kk = 0; kk < KSTEPS; ++kk)
    #pragma unroll
    for (int t = 0; t < NT; ++t)
      bf[kk][t] = *(const short8*)(BT + (size_t)(ch*NT*16 + t*16 + r)*K + kk*32 + g*8);
  for (int i = tid; i < 2*N; i += 512) red[i] = 0.f;
  __syncthreads();                     // red zeroed + absh ready
  if (APPLY){
    #pragma unroll
    for (int kk = 0; kk < KSTEPS; ++kk){
      #pragma unroll
      for (int j = 0; j < 8; ++j){
        float2 pab = absh[kk*32 + g*8 + j];
        float v = fmaxf(fmaf(bf2f((unsigned short)af[kk][j]), pab.x, pab.y), 0.f);
        af[kk][j] = (short)f2b(v);
      }
    }
  }
  f32x4 acc[NT];
  #pragma unroll
  for (int t = 0; t < NT; ++t) acc[t] = (f32x4){0.f,0.f,0.f,0.f};
  #pragma unroll
  for (int kk = 0; kk < KSTEPS; ++kk)
    #pragma unroll
    for (int t = 0; t < NT; ++t)
      acc[t] = __builtin_amdgcn_mfma_f32_16x16x32_bf16(af[kk], bf[kk][t], acc[t], 0, 0, 0);
  if (valid){
    #pragma unroll
    for (int t = 0; t < NT; ++t){
      int c = ch*NT*16 + t*16 + r;
      float ys = 0.f, yq = 0.f;
      #pragma unroll
      for (int j = 0; j < 4; ++j){
        float y = acc[t][j];
        Y[(size_t)(tile*16 + g*4 + j)*N + c] = (unsigned short)f2b(y);
        ys += y; yq += y*y;
      }
      ys += __shfl_xor(ys, 16); ys += __shfl_xor(ys, 32);
      yq += __shfl_xor(yq, 16); yq += __shfl_xor(yq, 32);
      if (g == 0){
        atomicAdd(&red[c], ys);
        atomicAdd(&red[N+c], yq);
      }
    }
  }
  __syncthreads();
  float* dstAcc = statsAcc + (size_t)(blockIdx.x & (SREP-1)) * (2*N);
  for (int i = tid; i < 2*N; i += 512) atomicAdd(&dstAcc[i], red[i]);
}

// ---------- apply: H' = relu(bn(Y)) as bf16 (N=128), grid-stride ----------
__global__ __launch_bounds__(256) void k_apply(const unsigned short* __restrict__ Y,
    const float* __restrict__ st, const float* __restrict__ gam,
    const float* __restrict__ bet, unsigned short* __restrict__ Hp){
  __shared__ float2 absh[128];
  compute_ab<128>(st, gam, bet, absh);
  __syncthreads();
  for (int i = blockIdx.x*256 + threadIdx.x; i < NN*64; i += gridDim.x*256){
    unsigned v = ((const unsigned*)Y)[i];
    int c = (i & 63)*2;
    float2 p0 = absh[c], p1 = absh[c+1];
    float o0 = fmaxf(fmaf(lof(v), p0.x, p0.y), 0.f);
    float o1 = fmaxf(fmaf(hif(v), p1.x, p1.y), 0.f);
    ((unsigned*)Hp)[i] = (unsigned)f2b(o0) | ((unsigned)f2b(o1) << 16);
  }
}

// ---------- final output: out = relu(bn(Y)), f32 (N=64), grid-stride ----------
__global__ __launch_bounds__(256) void k_final(const unsigned short* __restrict__ Y,
    const float* __restrict__ st, const float* __restrict__ gam,
    const float* __restrict__ bet, float* __restrict__ out){
  __shared__ float2 absh[64];
  compute_ab<64>(st, gam, bet, absh);
  __syncthreads();
  for (int i = blockIdx.x*256 + threadIdx.x; i < NN*32; i += gridDim.x*256){
    unsigned v = ((const unsigned*)Y)[i];
    int c = (i & 31)*2;
    float2 p0 = absh[c], p1 = absh[c+1];
    float o0 = fmaxf(fmaf(lof(v), p0.x, p0.y), 0.f);
    float o1 = fmaxf(fmaf(hif(v), p1.x, p1.y), 0.f);
    ((float2*)out)[i] = make_float2(o0, o1);
  }
}

extern "C" void kernel_launch(void* const* d_in, const int* in_sizes, int n_in,
                              void* d_out, int out_size, void* d_ws, size_t ws_size,
                              hipStream_t stream) {
  const float* features = (const float*)d_in[0];
  const int* src = (const int*)d_in[1];
  const int* dst = (const int*)d_in[2];
  const float *Wp[6], *gp[6], *bep[6];
  for (int l = 0; l < 3; ++l){
    int base = 3 + 8*l;
    Wp[2*l]    = (const float*)d_in[base+0];
    gp[2*l]    = (const float*)d_in[base+2];
    bep[2*l]   = (const float*)d_in[base+3];
    Wp[2*l+1]  = (const float*)d_in[base+4];
    gp[2*l+1]  = (const float*)d_in[base+6];
    bep[2*l+1] = (const float*)d_in[base+7];
  }

  size_t off = 0;
  char* base = (char*)d_ws;
  auto carve = [&](size_t bytes)->char* {
    char* q = base + off; off += (bytes + 255) & ~(size_t)255; return q;
  };
  // zero-init region: deg + total + 6 replicated stats buffers (contiguous)
  int* deg   = (int*)carve((size_t)NN*4);
  int* total = (int*)carve(4);
  float* stats[6];
  for (int i = 0; i < 6; ++i) stats[i] = (float*)carve((size_t)SREP*256*4);
  size_t zbytes = (size_t)(base + off - (char*)deg);   // multiple of 256

  int* row_off = (int*)carve((size_t)NN*4);
  int* cur     = (int*)carve((size_t)NN*4);
  int* col     = (int*)carve((size_t)(NE + 3*NN + 4096)*4);  // padded CSR + slack
  unsigned short* wt[6];
  for (int i = 0; i < 6; ++i) wt[i] = (unsigned short*)carve(128*128*2);
  unsigned short* H0 = (unsigned short*)carve((size_t)(NN+1)*128*2);  // gather table (dummy 0)
  unsigned short* Hp = (unsigned short*)carve((size_t)(NN+1)*128*2);  // gather table (dummy 0)
  unsigned short* X  = (unsigned short*)carve((size_t)NN*128*2);
  unsigned short* Y1 = (unsigned short*)carve((size_t)NN*128*2);
  unsigned short* Y2 = (unsigned short*)carve((size_t)NN*128*2);

  // fast zero of deg+total+stats
  int zn4 = (int)(zbytes >> 4);
  k_zero<<<(zn4 + 255)/256, 256, 0, stream>>>((uint4v*)deg, zn4);

  W6 jb;
  for (int i = 0; i < 6; ++i){ jb.w[i] = Wp[i]; jb.o[i] = wt[i]; }
  k_pre<<<8899, 256, 0, stream>>>(features, H0, Hp, dst, deg, jb);
  k_offsets<<<(NN+255)/256, 256, 0, stream>>>(deg, row_off, cur, col, total);
  k_fill<<<(NE+255)/256, 256, 0, stream>>>(src, dst, cur, col, NE);

  const int agg_grid = 196*8;          // 196 node-groups x 8 column chunks

  // ---- layer 0 ----
  k_agg<<<agg_grid, 256, 0, stream>>>(H0, row_off, deg, col, X);
  k_gemm<4,4,2,false><<<782, 512, 0, stream>>>(X, wt[0], nullptr, nullptr, nullptr, Y1, stats[0]);
  k_gemm<4,4,2,true ><<<782, 512, 0, stream>>>(Y1, wt[1], stats[0], gp[0], bep[0], Y2, stats[1]);
  k_apply<<<1563, 256, 0, stream>>>(Y2, stats[1], gp[1], bep[1], Hp);
  // ---- layer 1 ----
  k_agg<<<agg_grid, 256, 0, stream>>>(Hp, row_off, deg, col, X);
  k_gemm<4,4,2,false><<<782, 512, 0, stream>>>(X, wt[2], nullptr, nullptr, nullptr, Y1, stats[2]);
  k_gemm<4,4,2,true ><<<782, 512, 0, stream>>>(Y1, wt[3], stats[2], gp[2], bep[2], Y2, stats[3]);
  k_apply<<<1563, 256, 0, stream>>>(Y2, stats[3], gp[3], bep[3], H0);
  // ---- layer 2 ----
  k_agg<<<agg_grid, 256, 0, stream>>>(H0, row_off, deg, col, X);
  k_gemm<4,4,1,false><<<391, 512, 0, stream>>>(X, wt[4], nullptr, nullptr, nullptr, Y1, stats[4]);
  k_gemm<2,4,1,true ><<<391, 512, 0, stream>>>(Y1, wt[5], stats[4], gp[4], bep[4], Y2, stats[5]);
  k_final<<<782, 256, 0, stream>>>(Y2, stats[5], gp[5], bep[5], (float*)d_out);
}

// Round 16
// 326.340 us; speedup vs baseline: 1.4477x; 1.4477x over previous
//
#include <hip/hip_runtime.h>

#define NN 50000
#define NE 600000
#define SREP 64

typedef __attribute__((ext_vector_type(8))) short short8;
typedef __attribute__((ext_vector_type(4))) float f32x4;
typedef __attribute__((ext_vector_type(4))) unsigned uint4v;

__device__ __forceinline__ float bf2f(unsigned short u){
  union { unsigned int i; float f; } c; c.i = ((unsigned int)u) << 16; return c.f;
}
__device__ __forceinline__ float lof(unsigned v){
  union { unsigned int i; float f; } c; c.i = v << 16; return c.f;
}
__device__ __forceinline__ float hif(unsigned v){
  union { unsigned int i; float f; } c; c.i = v & 0xFFFF0000u; return c.f;
}
__device__ __forceinline__ unsigned short f2b(float f){
  union { float f; unsigned int i; } c; c.f = f;
  unsigned int i = c.i;
  return (unsigned short)((i + 0x7FFFu + ((i >> 16) & 1u)) >> 16);
}

// ---------- fast workspace zero ----------
__global__ __launch_bounds__(256) void k_zero(uint4v* __restrict__ p, int n4){
  int i = blockIdx.x*256 + threadIdx.x;
  if (i < n4) p[i] = (uint4v){0,0,0,0};
}

// ---------- per-block BN coefficient computation from replicated stats ----------
template<int N>
__device__ __forceinline__ void compute_ab(const float* __restrict__ st,
    const float* __restrict__ gam, const float* __restrict__ bet, float2* absh){
  int tid = threadIdx.x;
  if (tid < N){
    float s = 0.f, q = 0.f;
    #pragma unroll 16
    for (int r = 0; r < SREP; ++r){
      s += st[r*2*N + tid];
      q += st[r*2*N + N + tid];
    }
    float mu = s * (1.f/(float)NN);
    float var = fmaxf(q * (1.f/(float)NN) - mu*mu, 0.f);
    float a = gam[tid] * rsqrtf(var + 1e-5f);
    absh[tid] = make_float2(a, bet[tid] - mu*a);
  }
}

// ---------- fused preprocessing: cvt | hist | wconv | zero dummy rows ----------
struct W6 { const float* w[6]; unsigned short* o[6]; };
__global__ __launch_bounds__(256) void k_pre(const float* __restrict__ features,
    unsigned short* __restrict__ H0, unsigned short* __restrict__ Hp,
    const int* __restrict__ dst, int* __restrict__ deg, W6 jb){
  int b = blockIdx.x, tid = threadIdx.x;
  if (b < 6250){                       // cvt: NN*128 floats as float4 -> bf16x4
    int i = b*256 + tid;               // i < NN*32 exactly
    float4 v = ((const float4*)features)[i];
    uint2 o;
    o.x = (unsigned)f2b(v.x) | ((unsigned)f2b(v.y) << 16);
    o.y = (unsigned)f2b(v.z) | ((unsigned)f2b(v.w) << 16);
    ((uint2*)H0)[i] = o;
  } else if (b < 6250 + 2344){         // hist
    int i = (b - 6250)*256 + tid;
    if (i < NE) atomicAdd(&deg[dst[i]], 1);
  } else if (b < 6250 + 2344 + 304){   // weight transpose+convert, 6 jobs
    int i = (b - 8594)*256 + tid;
    if (i < 77824){
      int job, base, K, N;
      if (i < 65536){ job = i >> 14; base = job << 14; K = 128; N = 128; }
      else if (i < 73728){ job = 4; base = 65536; K = 128; N = 64; }
      else { job = 5; base = 73728; K = 64; N = 64; }
      int t = i - base;
      int k = t & (K-1);
      int n = t / K;
      jb.o[job][t] = f2b(jb.w[job][k*N + n]);
    }
  } else {                             // zero dummy row NN of both gather tables
    if (tid < 32){
      unsigned short* bp = (tid < 16) ? H0 : Hp;
      ((uint4v*)bp)[(size_t)NN*16 + (tid & 15)] = (uint4v){0,0,0,0};
    }
  }
}

// ---------- CSR offsets (block-local scan over PADDED degrees + pad-slot fill) ----------
__global__ void k_offsets(const int* __restrict__ deg, int* __restrict__ row_off,
                          int* __restrict__ cur, int* __restrict__ col,
                          int* __restrict__ total){
  __shared__ int ws[4];
  __shared__ int wbase[4];
  int tid = threadIdx.x, lane = tid & 63, wid = tid >> 6;
  int i = blockIdx.x*256 + tid;
  int v = (i < NN) ? deg[i] : 0;
  int vp = (v + 3) & ~3;               // padded degree
  int x = vp;
  #pragma unroll
  for (int o = 1; o < 64; o <<= 1){
    int t = __shfl_up(x, o);
    if (lane >= o) x += t;
  }
  if (lane == 63) ws[wid] = x;
  __syncthreads();
  if (tid == 0){
    int s0 = ws[0], s1 = ws[1], s2 = ws[2], s3 = ws[3];
    int b = atomicAdd(total, s0+s1+s2+s3);
    wbase[0] = b; wbase[1] = b+s0; wbase[2] = b+s0+s1; wbase[3] = b+s0+s1+s2;
  }
  __syncthreads();
  if (i < NN){
    int excl = wbase[wid] + x - vp;
    row_off[i] = excl;
    cur[i] = excl;
    for (int t = v; t < vp; ++t) col[excl + t] = NN;   // pad -> zero dummy node
  }
}

__global__ void k_fill(const int* __restrict__ src, const int* __restrict__ dst,
                       int* __restrict__ cur, int* __restrict__ col, int e){
  int i = blockIdx.x*blockDim.x + threadIdx.x;
  if (i >= e) return;
  int d = dst[i];
  int pos = atomicAdd(&cur[d], 1);
  col[pos] = src[i];
}

// ---------- aggregation (PURE ADD, per-thread quarter-row): x = h + mean(h[neigh]) ----------
// One node per QUAD of adjacent lanes: node = i>>2, chunk = i&3. Each thread owns
// a 64B quarter-row (one full cache line -> zero over-fetch; r15 lesson). The quad
// shares one broadcast int2 col load (col is 2.4MB, L2-hot); its 16x16B gathers
// cover the full 256B row. Per-thread loop, quad-convergent, no cross-lane ops;
// dp is a multiple of 4 -> exact unroll-2, 8 gathers in flight per thread.
// Table is post-activation (dummy row NN = 0), so CSR pad slots add 0.
__global__ __launch_bounds__(256) void k_agg(const unsigned short* __restrict__ T,
    const int* __restrict__ row_off, const int* __restrict__ deg,
    const int* __restrict__ col, unsigned short* __restrict__ X){
  int i = blockIdx.x*256 + threadIdx.x;
  if (i >= NN*4) return;
  int node = i >> 2, chunk = i & 3;
  int beg = row_off[node];             // multiple of 4
  int d = deg[node];
  int dp = (d + 3) & ~3;               // multiple of 4 (>= 0)
  const uint4v* tp = (const uint4v*)T; // 16 uint4v per 256B row
  size_t self = (size_t)node*16 + chunk*4;
  float s[32];
  #pragma unroll
  for (int j = 0; j < 32; ++j) s[j] = 0.f;
  auto ACC = [&](uint4v v, int o){
    s[o+0] += lof(v.x); s[o+1] += hif(v.x);
    s[o+2] += lof(v.y); s[o+3] += hif(v.y);
    s[o+4] += lof(v.z); s[o+5] += hif(v.z);
    s[o+6] += lof(v.w); s[o+7] += hif(v.w);
  };
  for (int e = 0; e < dp; e += 2){
    int2 cc = *(const int2*)(col + beg + e);   // quad-broadcast, L2-hot
    size_t b0 = (size_t)cc.x*16 + chunk*4;
    size_t b1 = (size_t)cc.y*16 + chunk*4;
    uint4v a0 = tp[b0], a1 = tp[b0+1], a2 = tp[b0+2], a3 = tp[b0+3];
    uint4v c0 = tp[b1], c1 = tp[b1+1], c2 = tp[b1+2], c3 = tp[b1+3];
    ACC(a0,0); ACC(a1,8); ACC(a2,16); ACC(a3,24);
    ACC(c0,0); ACC(c1,8); ACC(c2,16); ACC(c3,24);
  }
  uint4v h0 = tp[self], h1 = tp[self+1], h2 = tp[self+2], h3 = tp[self+3];
  float inv = 1.f / (float)(d > 0 ? d : 1);
  float hf[32] = {lof(h0.x),hif(h0.x),lof(h0.y),hif(h0.y),
                  lof(h0.z),hif(h0.z),lof(h0.w),hif(h0.w),
                  lof(h1.x),hif(h1.x),lof(h1.y),hif(h1.y),
                  lof(h1.z),hif(h1.z),lof(h1.w),hif(h1.w),
                  lof(h2.x),hif(h2.x),lof(h2.y),hif(h2.y),
                  lof(h2.z),hif(h2.z),lof(h2.w),hif(h2.w),
                  lof(h3.x),hif(h3.x),lof(h3.y),hif(h3.y),
                  lof(h3.z),hif(h3.z),lof(h3.w),hif(h3.w)};
  unsigned w[16];
  #pragma unroll
  for (int j = 0; j < 16; ++j){
    float x0 = hf[2*j]   + s[2*j]*inv;
    float x1 = hf[2*j+1] + s[2*j+1]*inv;
    w[j] = (unsigned)f2b(x0) | ((unsigned)f2b(x1) << 16);
  }
  uint4v* xp = (uint4v*)X + self;
  xp[0] = (uint4v){w[0], w[1], w[2], w[3]};
  xp[1] = (uint4v){w[4], w[5], w[6], w[7]};
  xp[2] = (uint4v){w[8], w[9], w[10], w[11]};
  xp[3] = (uint4v){w[12], w[13], w[14], w[15]};
}

// ---------- GEMM: 512-thread blocks, column-split; B panel per wave in regs ----------
// Y[NN][N] = act(A)[NN][K] @ BT[N][K]^T, fused BN stats; APPLY = BN+relu on A-load
template<int KSTEPS, int NT, int CS, bool APPLY>
__global__ __launch_bounds__(512) void k_gemm(const unsigned short* __restrict__ A,
    const unsigned short* __restrict__ BT,
    const float* __restrict__ stIn, const float* __restrict__ gam,
    const float* __restrict__ bet,
    unsigned short* __restrict__ Y, float* __restrict__ statsAcc){
  constexpr int K = KSTEPS*32;
  constexpr int N = CS*NT*16;
  constexpr int TILES = NN/16;         // 3125
  constexpr int TPB = (CS==2) ? 4 : 8;
  __shared__ float red[2*N];
  __shared__ float2 absh[K];
  if (APPLY) compute_ab<K>(stIn, gam, bet, absh);
  int tid = threadIdx.x;
  int lane = tid & 63, w = tid >> 6;
  int r = lane & 15, g = lane >> 4;
  int tile = blockIdx.x*TPB + ((CS==2) ? (w & 3) : w);
  int ch = (CS==2) ? (w >> 2) : 0;
  bool valid = (tile < TILES);
  int arow = valid ? tile*16 + r : 0;
  short8 af[KSTEPS];
  #pragma unroll
  for (int kk = 0; kk < KSTEPS; ++kk)
    af[kk] = *(const short8*)(A + (size_t)arow*K + kk*32 + g*8);
  short8 bf[KSTEPS][NT];
  #pragma unroll
  for (int kk = 0; kk < KSTEPS; ++kk)
    #pragma unroll
    for (int t = 0; t < NT; ++t)
      bf[kk][t] = *(const short8*)(BT + (size_t)(ch*NT*16 + t*16 + r)*K + kk*32 + g*8);
  for (int i = tid; i < 2*N; i += 512) red[i] = 0.f;
  __syncthreads();                     // red zeroed + absh ready
  if (APPLY){
    #pragma unroll
    for (int kk = 0; kk < KSTEPS; ++kk){
      #pragma unroll
      for (int j = 0; j < 8; ++j){
        float2 pab = absh[kk*32 + g*8 + j];
        float v = fmaxf(fmaf(bf2f((unsigned short)af[kk][j]), pab.x, pab.y), 0.f);
        af[kk][j] = (short)f2b(v);
      }
    }
  }
  f32x4 acc[NT];
  #pragma unroll
  for (int t = 0; t < NT; ++t) acc[t] = (f32x4){0.f,0.f,0.f,0.f};
  #pragma unroll
  for (int kk = 0; kk < KSTEPS; ++kk)
    #pragma unroll
    for (int t = 0; t < NT; ++t)
      acc[t] = __builtin_amdgcn_mfma_f32_16x16x32_bf16(af[kk], bf[kk][t], acc[t], 0, 0, 0);
  if (valid){
    #pragma unroll
    for (int t = 0; t < NT; ++t){
      int c = ch*NT*16 + t*16 + r;
      float ys = 0.f, yq = 0.f;
      #pragma unroll
      for (int j = 0; j < 4; ++j){
        float y = acc[t][j];
        Y[(size_t)(tile*16 + g*4 + j)*N + c] = (unsigned short)f2b(y);
        ys += y; yq += y*y;
      }
      ys += __shfl_xor(ys, 16); ys += __shfl_xor(ys, 32);
      yq += __shfl_xor(yq, 16); yq += __shfl_xor(yq, 32);
      if (g == 0){
        atomicAdd(&red[c], ys);
        atomicAdd(&red[N+c], yq);
      }
    }
  }
  __syncthreads();
  float* dstAcc = statsAcc + (size_t)(blockIdx.x & (SREP-1)) * (2*N);
  for (int i = tid; i < 2*N; i += 512) atomicAdd(&dstAcc[i], red[i]);
}

// ---------- apply: H' = relu(bn(Y)) as bf16 (N=128), grid-stride ----------
__global__ __launch_bounds__(256) void k_apply(const unsigned short* __restrict__ Y,
    const float* __restrict__ st, const float* __restrict__ gam,
    const float* __restrict__ bet, unsigned short* __restrict__ Hp){
  __shared__ float2 absh[128];
  compute_ab<128>(st, gam, bet, absh);
  __syncthreads();
  for (int i = blockIdx.x*256 + threadIdx.x; i < NN*64; i += gridDim.x*256){
    unsigned v = ((const unsigned*)Y)[i];
    int c = (i & 63)*2;
    float2 p0 = absh[c], p1 = absh[c+1];
    float o0 = fmaxf(fmaf(lof(v), p0.x, p0.y), 0.f);
    float o1 = fmaxf(fmaf(hif(v), p1.x, p1.y), 0.f);
    ((unsigned*)Hp)[i] = (unsigned)f2b(o0) | ((unsigned)f2b(o1) << 16);
  }
}

// ---------- final output: out = relu(bn(Y)), f32 (N=64), grid-stride ----------
__global__ __launch_bounds__(256) void k_final(const unsigned short* __restrict__ Y,
    const float* __restrict__ st, const float* __restrict__ gam,
    const float* __restrict__ bet, float* __restrict__ out){
  __shared__ float2 absh[64];
  compute_ab<64>(st, gam, bet, absh);
  __syncthreads();
  for (int i = blockIdx.x*256 + threadIdx.x; i < NN*32; i += gridDim.x*256){
    unsigned v = ((const unsigned*)Y)[i];
    int c = (i & 31)*2;
    float2 p0 = absh[c], p1 = absh[c+1];
    float o0 = fmaxf(fmaf(lof(v), p0.x, p0.y), 0.f);
    float o1 = fmaxf(fmaf(hif(v), p1.x, p1.y), 0.f);
    ((float2*)out)[i] = make_float2(o0, o1);
  }
}

extern "C" void kernel_launch(void* const* d_in, const int* in_sizes, int n_in,
                              void* d_out, int out_size, void* d_ws, size_t ws_size,
                              hipStream_t stream) {
  const float* features = (const float*)d_in[0];
  const int* src = (const int*)d_in[1];
  const int* dst = (const int*)d_in[2];
  const float *Wp[6], *gp[6], *bep[6];
  for (int l = 0; l < 3; ++l){
    int base = 3 + 8*l;
    Wp[2*l]    = (const float*)d_in[base+0];
    gp[2*l]    = (const float*)d_in[base+2];
    bep[2*l]   = (const float*)d_in[base+3];
    Wp[2*l+1]  = (const float*)d_in[base+4];
    gp[2*l+1]  = (const float*)d_in[base+6];
    bep[2*l+1] = (const float*)d_in[base+7];
  }

  size_t off = 0;
  char* base = (char*)d_ws;
  auto carve = [&](size_t bytes)->char* {
    char* q = base + off; off += (bytes + 255) & ~(size_t)255; return q;
  };
  // zero-init region: deg + total + 6 replicated stats buffers (contiguous)
  int* deg   = (int*)carve((size_t)NN*4);
  int* total = (int*)carve(4);
  float* stats[6];
  for (int i = 0; i < 6; ++i) stats[i] = (float*)carve((size_t)SREP*256*4);
  size_t zbytes = (size_t)(base + off - (char*)deg);   // multiple of 256

  int* row_off = (int*)carve((size_t)NN*4);
  int* cur     = (int*)carve((size_t)NN*4);
  int* col     = (int*)carve((size_t)(NE + 3*NN + 64)*4);  // padded CSR + slack
  unsigned short* wt[6];
  for (int i = 0; i < 6; ++i) wt[i] = (unsigned short*)carve(128*128*2);
  unsigned short* H0 = (unsigned short*)carve((size_t)(NN+1)*128*2);  // gather table (dummy 0)
  unsigned short* Hp = (unsigned short*)carve((size_t)(NN+1)*128*2);  // gather table (dummy 0)
  unsigned short* X  = (unsigned short*)carve((size_t)NN*128*2);
  unsigned short* Y1 = (unsigned short*)carve((size_t)NN*128*2);
  unsigned short* Y2 = (unsigned short*)carve((size_t)NN*128*2);

  // fast zero of deg+total+stats
  int zn4 = (int)(zbytes >> 4);
  k_zero<<<(zn4 + 255)/256, 256, 0, stream>>>((uint4v*)deg, zn4);

  W6 jb;
  for (int i = 0; i < 6; ++i){ jb.w[i] = Wp[i]; jb.o[i] = wt[i]; }
  k_pre<<<8899, 256, 0, stream>>>(features, H0, Hp, dst, deg, jb);
  k_offsets<<<(NN+255)/256, 256, 0, stream>>>(deg, row_off, cur, col, total);
  k_fill<<<(NE+255)/256, 256, 0, stream>>>(src, dst, cur, col, NE);

  const int agg_grid = (NN*4 + 255)/256;   // 782: one quarter-row per thread

  // ---- layer 0 ----
  k_agg<<<agg_grid, 256, 0, stream>>>(H0, row_off, deg, col, X);
  k_gemm<4,4,2,false><<<782, 512, 0, stream>>>(X, wt[0], nullptr, nullptr, nullptr, Y1, stats[0]);
  k_gemm<4,4,2,true ><<<782, 512, 0, stream>>>(Y1, wt[1], stats[0], gp[0], bep[0], Y2, stats[1]);
  k_apply<<<1563, 256, 0, stream>>>(Y2, stats[1], gp[1], bep[1], Hp);
  // ---- layer 1 ----
  k_agg<<<agg_grid, 256, 0, stream>>>(Hp, row_off, deg, col, X);
  k_gemm<4,4,2,false><<<782, 512, 0, stream>>>(X, wt[2], nullptr, nullptr, nullptr, Y1, stats[2]);
  k_gemm<4,4,2,true ><<<782, 512, 0, stream>>>(Y1, wt[3], stats[2], gp[2], bep[2], Y2, stats[3]);
  k_apply<<<1563, 256, 0, stream>>>(Y2, stats[3], gp[3], bep[3], H0);
  // ---- layer 2 ----
  k_agg<<<agg_grid, 256, 0, stream>>>(H0, row_off, deg, col, X);
  k_gemm<4,4,1,false><<<391, 512, 0, stream>>>(X, wt[4], nullptr, nullptr, nullptr, Y1, stats[4]);
  k_gemm<2,4,1,true ><<<391, 512, 0, stream>>>(Y1, wt[5], stats[4], gp[4], bep[4], Y2, stats[5]);
  k_final<<<782, 256, 0, stream>>>(Y2, stats[5], gp[5], bep[5], (float*)d_out);
}

// Round 17
// 289.714 us; speedup vs baseline: 1.6307x; 1.1264x over previous
//
#include <hip/hip_runtime.h>

#define NN 50000
#define NE 600000
#define SREP 32

typedef __attribute__((ext_vector_type(8))) short short8;
typedef __attribute__((ext_vector_type(4))) float f32x4;
typedef __attribute__((ext_vector_type(4))) unsigned uint4v;

__device__ __forceinline__ float bf2f(unsigned short u){
  union { unsigned int i; float f; } c; c.i = ((unsigned int)u) << 16; return c.f;
}
__device__ __forceinline__ float lof(unsigned v){
  union { unsigned int i; float f; } c; c.i = v << 16; return c.f;
}
__device__ __forceinline__ float hif(unsigned v){
  union { unsigned int i; float f; } c; c.i = v & 0xFFFF0000u; return c.f;
}
__device__ __forceinline__ unsigned short f2b(float f){
  union { float f; unsigned int i; } c; c.f = f;
  unsigned int i = c.i;
  return (unsigned short)((i + 0x7FFFu + ((i >> 16) & 1u)) >> 16);
}

// ---------- fast workspace zero ----------
__global__ __launch_bounds__(256) void k_zero(uint4v* __restrict__ p, int n4){
  int i = blockIdx.x*256 + threadIdx.x;
  if (i < n4) p[i] = (uint4v){0,0,0,0};
}

// ---------- per-block BN coefficient computation from replicated stats ----------
template<int N>
__device__ __forceinline__ void compute_ab(const float* __restrict__ st,
    const float* __restrict__ gam, const float* __restrict__ bet, float2* absh){
  int tid = threadIdx.x;
  if (tid < N){
    float s = 0.f, q = 0.f;
    #pragma unroll
    for (int r = 0; r < SREP; ++r){
      s += st[r*2*N + tid];
      q += st[r*2*N + N + tid];
    }
    float mu = s * (1.f/(float)NN);
    float var = fmaxf(q * (1.f/(float)NN) - mu*mu, 0.f);
    float a = gam[tid] * rsqrtf(var + 1e-5f);
    absh[tid] = make_float2(a, bet[tid] - mu*a);
  }
}

// ---------- fused preprocessing: cvt | hist | wconv ----------
struct W6 { const float* w[6]; unsigned short* o[6]; };
__global__ __launch_bounds__(256) void k_pre(const float* __restrict__ features,
    unsigned short* __restrict__ H0, const int* __restrict__ dst,
    int* __restrict__ deg, W6 jb){
  int b = blockIdx.x, tid = threadIdx.x;
  if (b < 6250){                       // cvt: NN*128 floats as float4 -> bf16x4
    int i = b*256 + tid;               // i < NN*32 exactly
    float4 v = ((const float4*)features)[i];
    uint2 o;
    o.x = (unsigned)f2b(v.x) | ((unsigned)f2b(v.y) << 16);
    o.y = (unsigned)f2b(v.z) | ((unsigned)f2b(v.w) << 16);
    ((uint2*)H0)[i] = o;
  } else if (b < 6250 + 2344){         // hist
    int i = (b - 6250)*256 + tid;
    if (i < NE) atomicAdd(&deg[dst[i]], 1);
  } else {                             // weight transpose+convert, 6 jobs
    int i = (b - 8594)*256 + tid;
    if (i < 77824){
      int job, base, K, N;
      if (i < 65536){ job = i >> 14; base = job << 14; K = 128; N = 128; }
      else if (i < 73728){ job = 4; base = 65536; K = 128; N = 64; }
      else { job = 5; base = 73728; K = 64; N = 64; }
      int t = i - base;
      int k = t & (K-1);
      int n = t / K;
      jb.o[job][t] = f2b(jb.w[job][k*N + n]);
    }
  }
}

// ---------- CSR offsets (block-local scan over PADDED degrees + pad-slot fill) ----------
__global__ void k_offsets(const int* __restrict__ deg, int* __restrict__ row_off,
                          int* __restrict__ cur, int* __restrict__ col,
                          int* __restrict__ total){
  __shared__ int ws[4];
  __shared__ int wbase[4];
  int tid = threadIdx.x, lane = tid & 63, wid = tid >> 6;
  int i = blockIdx.x*256 + tid;
  int v = (i < NN) ? deg[i] : 0;
  int vp = (v + 3) & ~3;               // padded degree
  int x = vp;
  #pragma unroll
  for (int o = 1; o < 64; o <<= 1){
    int t = __shfl_up(x, o);
    if (lane >= o) x += t;
  }
  if (lane == 63) ws[wid] = x;
  __syncthreads();
  if (tid == 0){
    int s0 = ws[0], s1 = ws[1], s2 = ws[2], s3 = ws[3];
    int b = atomicAdd(total, s0+s1+s2+s3);
    wbase[0] = b; wbase[1] = b+s0; wbase[2] = b+s0+s1; wbase[3] = b+s0+s1+s2;
  }
  __syncthreads();
  if (i < NN){
    int excl = wbase[wid] + x - vp;
    row_off[i] = excl;
    cur[i] = excl;
    for (int t = v; t < vp; ++t) col[excl + t] = NN;   // pad -> zero dummy node
  }
}

__global__ void k_fill(const int* __restrict__ src, const int* __restrict__ dst,
                       int* __restrict__ cur, int* __restrict__ col, int e){
  int i = blockIdx.x*blockDim.x + threadIdx.x;
  if (i >= e) return;
  int d = dst[i];
  int pos = atomicAdd(&cur[d], 1);
  col[pos] = src[i];
}

// ---------- aggregation: x = act(h) + mean(act(h[neigh])) ----------
// TWO nodes per wave (one per 32-lane half). Within a half: p=hl&15 covers the
// 128 cols (uint4/lane), qq=hl>>4 picks odd/even edge. Per batch, 4 steps x 2
// quarters = 8 row-gathers in flight per half (16/wave). Shuffles source only
// within the executing half -> safe under divergence (round-4 lesson).
// Pad edges gather the zero dummy row; with APPLY each contributes relu(b_c),
// subtracted analytically. Invalid (beyond-steps) slots gather the dummy row
// but are excluded from ACC.
template<bool APPLY>
__global__ __launch_bounds__(256) void k_agg(const unsigned short* __restrict__ H,
    const float* __restrict__ st, const float* __restrict__ gam,
    const float* __restrict__ bet, const int* __restrict__ row_off,
    const int* __restrict__ deg, const int* __restrict__ col,
    unsigned short* __restrict__ X){
  __shared__ float2 absh[128];
  if (APPLY){ compute_ab<128>(st, gam, bet, absh); __syncthreads(); }
  int lane = threadIdx.x & 63;
  int wave = threadIdx.x >> 6;
  int half = lane >> 5, hl = lane & 31;
  int p = hl & 15, qq = hl >> 4;
  float ac[8], bc[8];
  if (APPLY){
    #pragma unroll
    for (int e = 0; e < 8; ++e){ float2 t = absh[p*8 + e]; ac[e] = t.x; bc[e] = t.y; }
  }
  const uint4* hp4 = (const uint4*)H;
  int P = blockIdx.x*4 + wave;         // 0..24999 (grid 6250)
  int node = 2*P + half;               // < 50000 exactly
  int beg = row_off[node];
  int d = deg[node];
  int dp = (d + 3) & ~3;
  float s[8];
  #pragma unroll
  for (int e = 0; e < 8; ++e) s[e] = 0.f;
  auto ACC = [&](uint4 v){
    float x;
    x = lof(v.x); if (APPLY) x = fmaxf(fmaf(x,ac[0],bc[0]),0.f); s[0] += x;
    x = hif(v.x); if (APPLY) x = fmaxf(fmaf(x,ac[1],bc[1]),0.f); s[1] += x;
    x = lof(v.y); if (APPLY) x = fmaxf(fmaf(x,ac[2],bc[2]),0.f); s[2] += x;
    x = hif(v.y); if (APPLY) x = fmaxf(fmaf(x,ac[3],bc[3]),0.f); s[3] += x;
    x = lof(v.z); if (APPLY) x = fmaxf(fmaf(x,ac[4],bc[4]),0.f); s[4] += x;
    x = hif(v.z); if (APPLY) x = fmaxf(fmaf(x,ac[5],bc[5]),0.f); s[5] += x;
    x = lof(v.w); if (APPLY) x = fmaxf(fmaf(x,ac[6],bc[6]),0.f); s[6] += x;
    x = hif(v.w); if (APPLY) x = fmaxf(fmaf(x,ac[7],bc[7]),0.f); s[7] += x;
  };
  for (int base = 0; base < dp; base += 32){
    int wdp = dp - base; if (wdp > 32) wdp = 32;     // multiple of 4
    int cvs = (hl < wdp) ? col[beg + base + hl] : NN;
    int steps = wdp >> 1;                            // edges per quarter
    for (int s0 = 0; s0 < steps; s0 += 4){
      int idx[4], val[4];
      #pragma unroll
      for (int u = 0; u < 4; ++u){
        int stp = s0 + u;
        int v = (stp < steps);
        int e = v ? (2*stp + qq) : 0;
        int ix = __shfl(cvs, 32*half + e);           // in-half source, all-active
        idx[u] = v ? ix : NN;
        val[u] = v;
      }
      uint4 vv[4];
      #pragma unroll
      for (int u = 0; u < 4; ++u) vv[u] = hp4[(size_t)idx[u]*16 + p];
      #pragma unroll
      for (int u = 0; u < 4; ++u) if (val[u]) ACC(vv[u]);
    }
  }
  #pragma unroll
  for (int e = 0; e < 8; ++e) s[e] += __shfl_xor(s[e], 16);   // combine qq pair (stays in half)
  if (qq == 0){
    uint4 hv = hp4[(size_t)node*16 + p];
    float inv = 1.f / (float)(d > 0 ? d : 1);
    float npad = (float)(dp - d);
    float h[8] = {lof(hv.x),hif(hv.x),lof(hv.y),hif(hv.y),
                  lof(hv.z),hif(hv.z),lof(hv.w),hif(hv.w)};
    unsigned w[4];
    #pragma unroll
    for (int u = 0; u < 4; ++u){
      float x0 = h[2*u], x1 = h[2*u+1];
      float s0 = s[2*u], s1 = s[2*u+1];
      if (APPLY){
        x0 = fmaxf(fmaf(x0,ac[2*u],bc[2*u]),0.f);
        x1 = fmaxf(fmaf(x1,ac[2*u+1],bc[2*u+1]),0.f);
        s0 -= npad * fmaxf(bc[2*u], 0.f);     // remove pad-edge relu(b) terms
        s1 -= npad * fmaxf(bc[2*u+1], 0.f);
      }
      x0 += s0*inv;
      x1 += s1*inv;
      w[u] = (unsigned)f2b(x0) | ((unsigned)f2b(x1) << 16);
    }
    ((uint4*)X)[(size_t)node*16 + p] = make_uint4(w[0], w[1], w[2], w[3]);
  }
}

// ---------- GEMM: 512-thread blocks, column-split; B panel per wave in regs ----------
// Y[NN][N] = act(A)[NN][K] @ BT[N][K]^T, fused BN stats; APPLY = BN+relu on A-load.
// CS=2: waves 0-3 cols 0-63 of tiles b*4+w, waves 4-7 cols 64-127 (same tiles).
// CS=1: 8 tiles per block, each wave all 64 cols. ~120 VGPR -> 4 waves/SIMD.
template<int KSTEPS, int NT, int CS, bool APPLY>
__global__ __launch_bounds__(512) void k_gemm(const unsigned short* __restrict__ A,
    const unsigned short* __restrict__ BT,
    const float* __restrict__ stIn, const float* __restrict__ gam,
    const float* __restrict__ bet,
    unsigned short* __restrict__ Y, float* __restrict__ statsAcc){
  constexpr int K = KSTEPS*32;
  constexpr int N = CS*NT*16;
  constexpr int TILES = NN/16;         // 3125
  constexpr int TPB = (CS==2) ? 4 : 8;
  __shared__ float red[2*N];
  __shared__ float2 absh[K];
  if (APPLY) compute_ab<K>(stIn, gam, bet, absh);
  int tid = threadIdx.x;
  int lane = tid & 63, w = tid >> 6;
  int r = lane & 15, g = lane >> 4;
  int tile = blockIdx.x*TPB + ((CS==2) ? (w & 3) : w);
  int ch = (CS==2) ? (w >> 2) : 0;
  bool valid = (tile < TILES);
  int arow = valid ? tile*16 + r : 0;
  short8 af[KSTEPS];
  #pragma unroll
  for (int kk = 0; kk < KSTEPS; ++kk)
    af[kk] = *(const short8*)(A + (size_t)arow*K + kk*32 + g*8);
  short8 bf[KSTEPS][NT];
  #pragma unroll
  for (int kk = 0; kk < KSTEPS; ++kk)
    #pragma unroll
    for (int t = 0; t < NT; ++t)
      bf[kk][t] = *(const short8*)(BT + (size_t)(ch*NT*16 + t*16 + r)*K + kk*32 + g*8);
  for (int i = tid; i < 2*N; i += 512) red[i] = 0.f;
  __syncthreads();                     // red zeroed + absh ready
  if (APPLY){
    #pragma unroll
    for (int kk = 0; kk < KSTEPS; ++kk){
      #pragma unroll
      for (int j = 0; j < 8; ++j){
        float2 pab = absh[kk*32 + g*8 + j];
        float v = fmaxf(fmaf(bf2f((unsigned short)af[kk][j]), pab.x, pab.y), 0.f);
        af[kk][j] = (short)f2b(v);
      }
    }
  }
  f32x4 acc[NT];
  #pragma unroll
  for (int t = 0; t < NT; ++t) acc[t] = (f32x4){0.f,0.f,0.f,0.f};
  #pragma unroll
  for (int kk = 0; kk < KSTEPS; ++kk)
    #pragma unroll
    for (int t = 0; t < NT; ++t)
      acc[t] = __builtin_amdgcn_mfma_f32_16x16x32_bf16(af[kk], bf[kk][t], acc[t], 0, 0, 0);
  if (valid){
    #pragma unroll
    for (int t = 0; t < NT; ++t){
      int c = ch*NT*16 + t*16 + r;
      float ys = 0.f, yq = 0.f;
      #pragma unroll
      for (int j = 0; j < 4; ++j){
        float y = acc[t][j];
        Y[(size_t)(tile*16 + g*4 + j)*N + c] = (unsigned short)f2b(y);
        ys += y; yq += y*y;
      }
      ys += __shfl_xor(ys, 16); ys += __shfl_xor(ys, 32);
      yq += __shfl_xor(yq, 16); yq += __shfl_xor(yq, 32);
      if (g == 0){
        atomicAdd(&red[c], ys);
        atomicAdd(&red[N+c], yq);
      }
    }
  }
  __syncthreads();
  float* dstAcc = statsAcc + (size_t)(blockIdx.x & (SREP-1)) * (2*N);
  for (int i = tid; i < 2*N; i += 512) atomicAdd(&dstAcc[i], red[i]);
}

// ---------- final output: out = relu(bn(Y)), f32 (N=64), grid-stride ----------
__global__ __launch_bounds__(256) void k_final(const unsigned short* __restrict__ Y,
    const float* __restrict__ st, const float* __restrict__ gam,
    const float* __restrict__ bet, float* __restrict__ out){
  __shared__ float2 absh[64];
  compute_ab<64>(st, gam, bet, absh);
  __syncthreads();
  for (int i = blockIdx.x*256 + threadIdx.x; i < NN*32; i += gridDim.x*256){
    unsigned v = ((const unsigned*)Y)[i];
    int c = (i & 31)*2;
    float2 p0 = absh[c], p1 = absh[c+1];
    float o0 = fmaxf(fmaf(lof(v), p0.x, p0.y), 0.f);
    float o1 = fmaxf(fmaf(hif(v), p1.x, p1.y), 0.f);
    ((float2*)out)[i] = make_float2(o0, o1);
  }
}

extern "C" void kernel_launch(void* const* d_in, const int* in_sizes, int n_in,
                              void* d_out, int out_size, void* d_ws, size_t ws_size,
                              hipStream_t stream) {
  const float* features = (const float*)d_in[0];
  const int* src = (const int*)d_in[1];
  const int* dst = (const int*)d_in[2];
  const float *Wp[6], *gp[6], *bep[6];
  for (int l = 0; l < 3; ++l){
    int base = 3 + 8*l;
    Wp[2*l]    = (const float*)d_in[base+0];
    gp[2*l]    = (const float*)d_in[base+2];
    bep[2*l]   = (const float*)d_in[base+3];
    Wp[2*l+1]  = (const float*)d_in[base+4];
    gp[2*l+1]  = (const float*)d_in[base+6];
    bep[2*l+1] = (const float*)d_in[base+7];
  }

  size_t off = 0;
  char* base = (char*)d_ws;
  auto carve = [&](size_t bytes)->char* {
    char* q = base + off; off += (bytes + 255) & ~(size_t)255; return q;
  };
  // zero-init region: deg + total + 6 replicated stats buffers (contiguous)
  int* deg   = (int*)carve((size_t)NN*4);
  int* total = (int*)carve(4);
  float* stats[6];
  for (int i = 0; i < 6; ++i) stats[i] = (float*)carve((size_t)SREP*256*4);
  size_t zbytes = (size_t)(base + off - (char*)deg);   // multiple of 256

  int* row_off = (int*)carve((size_t)NN*4);
  int* cur     = (int*)carve((size_t)NN*4);
  int* col     = (int*)carve((size_t)(NE + 3*NN)*4);   // padded CSR
  unsigned short* wt[6];
  for (int i = 0; i < 6; ++i) wt[i] = (unsigned short*)carve(128*128*2);
  unsigned short* H0 = (unsigned short*)carve((size_t)(NN+1)*128*2);
  unsigned short* X  = (unsigned short*)carve((size_t)(NN+1)*128*2);
  unsigned short* Y1 = (unsigned short*)carve((size_t)(NN+1)*128*2);
  unsigned short* Y2 = (unsigned short*)carve((size_t)(NN+1)*128*2);

  // fast zero of deg+total+stats
  int zn4 = (int)(zbytes >> 4);
  k_zero<<<(zn4 + 255)/256, 256, 0, stream>>>((uint4v*)deg, zn4);

  W6 jb;
  for (int i = 0; i < 6; ++i){ jb.w[i] = Wp[i]; jb.o[i] = wt[i]; }
  k_pre<<<8898, 256, 0, stream>>>(features, H0, dst, deg, jb);
  k_offsets<<<(NN+255)/256, 256, 0, stream>>>(deg, row_off, cur, col, total);
  k_fill<<<(NE+255)/256, 256, 0, stream>>>(src, dst, cur, col, NE);

  const int agg_grid = 6250;           // 6250 blocks x 4 waves x 2 nodes = 50000

  // ---- layer 0 ----
  k_agg<false><<<agg_grid, 256, 0, stream>>>(H0, nullptr, nullptr, nullptr, row_off, deg, col, X);
  k_gemm<4,4,2,false><<<782, 512, 0, stream>>>(X, wt[0], nullptr, nullptr, nullptr, Y1, stats[0]);
  k_gemm<4,4,2,true ><<<782, 512, 0, stream>>>(Y1, wt[1], stats[0], gp[0], bep[0], Y2, stats[1]);
  // ---- layer 1 ----
  k_agg<true ><<<agg_grid, 256, 0, stream>>>(Y2, stats[1], gp[1], bep[1], row_off, deg, col, X);
  k_gemm<4,4,2,false><<<782, 512, 0, stream>>>(X, wt[2], nullptr, nullptr, nullptr, Y1, stats[2]);
  k_gemm<4,4,2,true ><<<782, 512, 0, stream>>>(Y1, wt[3], stats[2], gp[2], bep[2], Y2, stats[3]);
  // ---- layer 2 ----
  k_agg<true ><<<agg_grid, 256, 0, stream>>>(Y2, stats[3], gp[3], bep[3], row_off, deg, col, X);
  k_gemm<4,4,1,false><<<391, 512, 0, stream>>>(X, wt[4], nullptr, nullptr, nullptr, Y1, stats[4]);
  k_gemm<2,4,1,true ><<<391, 512, 0, stream>>>(Y1, wt[5], stats[4], gp[4], bep[4], Y2, stats[5]);
  k_final<<<782, 256, 0, stream>>>(Y2, stats[5], gp[5], bep[5], (float*)d_out);
}

// Round 18
// 261.997 us; speedup vs baseline: 1.8032x; 1.1058x over previous
//
#include <hip/hip_runtime.h>

#define NN 50000
#define NE 600000
#define SREP 32

typedef __attribute__((ext_vector_type(8))) short short8;
typedef __attribute__((ext_vector_type(4))) float f32x4;
typedef __attribute__((ext_vector_type(4))) unsigned uint4v;

__device__ __forceinline__ float bf2f(unsigned short u){
  union { unsigned int i; float f; } c; c.i = ((unsigned int)u) << 16; return c.f;
}
__device__ __forceinline__ float lof(unsigned v){
  union { unsigned int i; float f; } c; c.i = v << 16; return c.f;
}
__device__ __forceinline__ float hif(unsigned v){
  union { unsigned int i; float f; } c; c.i = v & 0xFFFF0000u; return c.f;
}
__device__ __forceinline__ unsigned short f2b(float f){
  union { float f; unsigned int i; } c; c.f = f;
  unsigned int i = c.i;
  return (unsigned short)((i + 0x7FFFu + ((i >> 16) & 1u)) >> 16);
}

// ---------- fast workspace zero ----------
__global__ __launch_bounds__(256) void k_zero(uint4v* __restrict__ p, int n4){
  int i = blockIdx.x*256 + threadIdx.x;
  if (i < n4) p[i] = (uint4v){0,0,0,0};
}

// ---------- per-block BN coefficient computation from replicated stats ----------
template<int N>
__device__ __forceinline__ void compute_ab(const float* __restrict__ st,
    const float* __restrict__ gam, const float* __restrict__ bet, float2* absh){
  int tid = threadIdx.x;
  if (tid < N){
    float s = 0.f, q = 0.f;
    #pragma unroll
    for (int r = 0; r < SREP; ++r){
      s += st[r*2*N + tid];
      q += st[r*2*N + N + tid];
    }
    float mu = s * (1.f/(float)NN);
    float var = fmaxf(q * (1.f/(float)NN) - mu*mu, 0.f);
    float a = gam[tid] * rsqrtf(var + 1e-5f);
    absh[tid] = make_float2(a, bet[tid] - mu*a);
  }
}

// ---------- fused preprocessing: cvt | hist | wconv ----------
struct W6 { const float* w[6]; unsigned short* o[6]; };
__global__ __launch_bounds__(256) void k_pre(const float* __restrict__ features,
    unsigned short* __restrict__ H0, const int* __restrict__ dst,
    int* __restrict__ deg, W6 jb){
  int b = blockIdx.x, tid = threadIdx.x;
  if (b < 6250){                       // cvt: NN*128 floats as float4 -> bf16x4
    int i = b*256 + tid;               // i < NN*32 exactly
    float4 v = ((const float4*)features)[i];
    uint2 o;
    o.x = (unsigned)f2b(v.x) | ((unsigned)f2b(v.y) << 16);
    o.y = (unsigned)f2b(v.z) | ((unsigned)f2b(v.w) << 16);
    ((uint2*)H0)[i] = o;
  } else if (b < 6250 + 2344){         // hist
    int i = (b - 6250)*256 + tid;
    if (i < NE) atomicAdd(&deg[dst[i]], 1);
  } else {                             // weight transpose+convert, 6 jobs
    int i = (b - 8594)*256 + tid;
    if (i < 77824){
      int job, base, K, N;
      if (i < 65536){ job = i >> 14; base = job << 14; K = 128; N = 128; }
      else if (i < 73728){ job = 4; base = 65536; K = 128; N = 64; }
      else { job = 5; base = 73728; K = 64; N = 64; }
      int t = i - base;
      int k = t & (K-1);
      int n = t / K;
      jb.o[job][t] = f2b(jb.w[job][k*N + n]);
    }
  }
}

// ---------- CSR offsets (block-local scan over PADDED degrees + pad-slot fill) ----------
__global__ void k_offsets(const int* __restrict__ deg, int* __restrict__ row_off,
                          int* __restrict__ cur, int* __restrict__ col,
                          int* __restrict__ total){
  __shared__ int ws[4];
  __shared__ int wbase[4];
  int tid = threadIdx.x, lane = tid & 63, wid = tid >> 6;
  int i = blockIdx.x*256 + tid;
  int v = (i < NN) ? deg[i] : 0;
  int vp = (v + 3) & ~3;               // padded degree
  int x = vp;
  #pragma unroll
  for (int o = 1; o < 64; o <<= 1){
    int t = __shfl_up(x, o);
    if (lane >= o) x += t;
  }
  if (lane == 63) ws[wid] = x;
  __syncthreads();
  if (tid == 0){
    int s0 = ws[0], s1 = ws[1], s2 = ws[2], s3 = ws[3];
    int b = atomicAdd(total, s0+s1+s2+s3);
    wbase[0] = b; wbase[1] = b+s0; wbase[2] = b+s0+s1; wbase[3] = b+s0+s1+s2;
  }
  __syncthreads();
  if (i < NN){
    int excl = wbase[wid] + x - vp;
    row_off[i] = excl;
    cur[i] = excl;
    for (int t = v; t < vp; ++t) col[excl + t] = NN;   // pad -> zero dummy node
  }
}

__global__ void k_fill(const int* __restrict__ src, const int* __restrict__ dst,
                       int* __restrict__ cur, int* __restrict__ col, int e){
  int i = blockIdx.x*blockDim.x + threadIdx.x;
  if (i >= e) return;
  int d = dst[i];
  int pos = atomicAdd(&cur[d], 1);
  col[pos] = src[i];
}

// ---------- aggregation: x = act(h) + mean(act(h[neigh])) ----------
// TWO nodes per wave (one per 32-lane half). Within a half: p=hl&15 covers the
// 128 cols (uint4/lane), qq=hl>>4 picks odd/even edge. Per batch, 4 steps x 2
// quarters = 8 row-gathers in flight per half (16/wave). Shuffles source only
// within the executing half -> safe under divergence (round-4 lesson).
// Pad edges gather the zero dummy row; with APPLY each contributes relu(b_c),
// subtracted analytically. Invalid (beyond-steps) slots gather the dummy row
// but are excluded from ACC.
template<bool APPLY>
__global__ __launch_bounds__(256) void k_agg(const unsigned short* __restrict__ H,
    const float* __restrict__ st, const float* __restrict__ gam,
    const float* __restrict__ bet, const int* __restrict__ row_off,
    const int* __restrict__ deg, const int* __restrict__ col,
    unsigned short* __restrict__ X){
  __shared__ float2 absh[128];
  if (APPLY){ compute_ab<128>(st, gam, bet, absh); __syncthreads(); }
  int lane = threadIdx.x & 63;
  int wave = threadIdx.x >> 6;
  int half = lane >> 5, hl = lane & 31;
  int p = hl & 15, qq = hl >> 4;
  float ac[8], bc[8];
  if (APPLY){
    #pragma unroll
    for (int e = 0; e < 8; ++e){ float2 t = absh[p*8 + e]; ac[e] = t.x; bc[e] = t.y; }
  }
  const uint4* hp4 = (const uint4*)H;
  int P = blockIdx.x*4 + wave;         // 0..24999 (grid 6250)
  int node = 2*P + half;               // < 50000 exactly
  int beg = row_off[node];
  int d = deg[node];
  int dp = (d + 3) & ~3;
  float s[8];
  #pragma unroll
  for (int e = 0; e < 8; ++e) s[e] = 0.f;
  auto ACC = [&](uint4 v){
    float x;
    x = lof(v.x); if (APPLY) x = fmaxf(fmaf(x,ac[0],bc[0]),0.f); s[0] += x;
    x = hif(v.x); if (APPLY) x = fmaxf(fmaf(x,ac[1],bc[1]),0.f); s[1] += x;
    x = lof(v.y); if (APPLY) x = fmaxf(fmaf(x,ac[2],bc[2]),0.f); s[2] += x;
    x = hif(v.y); if (APPLY) x = fmaxf(fmaf(x,ac[3],bc[3]),0.f); s[3] += x;
    x = lof(v.z); if (APPLY) x = fmaxf(fmaf(x,ac[4],bc[4]),0.f); s[4] += x;
    x = hif(v.z); if (APPLY) x = fmaxf(fmaf(x,ac[5],bc[5]),0.f); s[5] += x;
    x = lof(v.w); if (APPLY) x = fmaxf(fmaf(x,ac[6],bc[6]),0.f); s[6] += x;
    x = hif(v.w); if (APPLY) x = fmaxf(fmaf(x,ac[7],bc[7]),0.f); s[7] += x;
  };
  for (int base = 0; base < dp; base += 32){
    int wdp = dp - base; if (wdp > 32) wdp = 32;     // multiple of 4
    int cvs = (hl < wdp) ? col[beg + base + hl] : NN;
    int steps = wdp >> 1;                            // edges per quarter
    for (int s0 = 0; s0 < steps; s0 += 4){
      int idx[4], val[4];
      #pragma unroll
      for (int u = 0; u < 4; ++u){
        int stp = s0 + u;
        int v = (stp < steps);
        int e = v ? (2*stp + qq) : 0;
        int ix = __shfl(cvs, 32*half + e);           // in-half source, all-active
        idx[u] = v ? ix : NN;
        val[u] = v;
      }
      uint4 vv[4];
      #pragma unroll
      for (int u = 0; u < 4; ++u) vv[u] = hp4[(size_t)idx[u]*16 + p];
      #pragma unroll
      for (int u = 0; u < 4; ++u) if (val[u]) ACC(vv[u]);
    }
  }
  #pragma unroll
  for (int e = 0; e < 8; ++e) s[e] += __shfl_xor(s[e], 16);   // combine qq pair (stays in half)
  if (qq == 0){
    uint4 hv = hp4[(size_t)node*16 + p];
    float inv = 1.f / (float)(d > 0 ? d : 1);
    float npad = (float)(dp - d);
    float h[8] = {lof(hv.x),hif(hv.x),lof(hv.y),hif(hv.y),
                  lof(hv.z),hif(hv.z),lof(hv.w),hif(hv.w)};
    unsigned w[4];
    #pragma unroll
    for (int u = 0; u < 4; ++u){
      float x0 = h[2*u], x1 = h[2*u+1];
      float s0 = s[2*u], s1 = s[2*u+1];
      if (APPLY){
        x0 = fmaxf(fmaf(x0,ac[2*u],bc[2*u]),0.f);
        x1 = fmaxf(fmaf(x1,ac[2*u+1],bc[2*u+1]),0.f);
        s0 -= npad * fmaxf(bc[2*u], 0.f);     // remove pad-edge relu(b) terms
        s1 -= npad * fmaxf(bc[2*u+1], 0.f);
      }
      x0 += s0*inv;
      x1 += s1*inv;
      w[u] = (unsigned)f2b(x0) | ((unsigned)f2b(x1) << 16);
    }
    ((uint4*)X)[(size_t)node*16 + p] = make_uint4(w[0], w[1], w[2], w[3]);
  }
}

// ---------- GEMM: 512-thread blocks, column-split, TWO 16-row tiles per wave ----------
// Y[NN][N] = act(A)[NN][K] @ BT[N][K]^T, fused BN stats; APPLY = BN+relu on A-load.
// CS=2: waves 0-3 tiles b*8+(w&3)*2+{0,1} cols 0-63; waves 4-7 same tiles cols 64-127.
// CS=1: 16 tiles per block, wave w covers tiles b*16+w*2+{0,1}, all 64 cols.
// Each B fragment feeds 2 MFMAs (2x reuse); 2 independent A-chains per wave hide
// each other's load latency (round-17 finding: VGPR=52, B not held resident).
template<int KSTEPS, int NT, int CS, bool APPLY>
__global__ __launch_bounds__(512) void k_gemm(const unsigned short* __restrict__ A,
    const unsigned short* __restrict__ BT,
    const float* __restrict__ stIn, const float* __restrict__ gam,
    const float* __restrict__ bet,
    unsigned short* __restrict__ Y, float* __restrict__ statsAcc){
  constexpr int K = KSTEPS*32;
  constexpr int N = CS*NT*16;
  constexpr int TILES = NN/16;         // 3125
  constexpr int TPB = (CS==2) ? 8 : 16;
  __shared__ float red[2*N];
  __shared__ float2 absh[K];
  if (APPLY) compute_ab<K>(stIn, gam, bet, absh);
  int tid = threadIdx.x;
  int lane = tid & 63, w = tid >> 6;
  int r = lane & 15, g = lane >> 4;
  int tile0 = blockIdx.x*TPB + ((CS==2) ? (w & 3)*2 : w*2);
  int ch = (CS==2) ? (w >> 2) : 0;
  bool valid[2] = { tile0 < TILES, tile0 + 1 < TILES };
  short8 af[2][KSTEPS];
  #pragma unroll
  for (int tm = 0; tm < 2; ++tm){
    int arow = valid[tm] ? (tile0 + tm)*16 + r : 0;
    #pragma unroll
    for (int kk = 0; kk < KSTEPS; ++kk)
      af[tm][kk] = *(const short8*)(A + (size_t)arow*K + kk*32 + g*8);
  }
  short8 bf[KSTEPS][NT];
  #pragma unroll
  for (int kk = 0; kk < KSTEPS; ++kk)
    #pragma unroll
    for (int t = 0; t < NT; ++t)
      bf[kk][t] = *(const short8*)(BT + (size_t)(ch*NT*16 + t*16 + r)*K + kk*32 + g*8);
  for (int i = tid; i < 2*N; i += 512) red[i] = 0.f;
  __syncthreads();                     // red zeroed + absh ready
  if (APPLY){
    #pragma unroll
    for (int tm = 0; tm < 2; ++tm)
      #pragma unroll
      for (int kk = 0; kk < KSTEPS; ++kk){
        #pragma unroll
        for (int j = 0; j < 8; ++j){
          float2 pab = absh[kk*32 + g*8 + j];
          float v = fmaxf(fmaf(bf2f((unsigned short)af[tm][kk][j]), pab.x, pab.y), 0.f);
          af[tm][kk][j] = (short)f2b(v);
        }
      }
  }
  f32x4 acc[2][NT];
  #pragma unroll
  for (int tm = 0; tm < 2; ++tm)
    #pragma unroll
    for (int t = 0; t < NT; ++t) acc[tm][t] = (f32x4){0.f,0.f,0.f,0.f};
  #pragma unroll
  for (int kk = 0; kk < KSTEPS; ++kk)
    #pragma unroll
    for (int t = 0; t < NT; ++t){
      acc[0][t] = __builtin_amdgcn_mfma_f32_16x16x32_bf16(af[0][kk], bf[kk][t], acc[0][t], 0, 0, 0);
      acc[1][t] = __builtin_amdgcn_mfma_f32_16x16x32_bf16(af[1][kk], bf[kk][t], acc[1][t], 0, 0, 0);
    }
  #pragma unroll
  for (int t = 0; t < NT; ++t){
    int c = ch*NT*16 + t*16 + r;
    float ys = 0.f, yq = 0.f;
    #pragma unroll
    for (int tm = 0; tm < 2; ++tm){
      if (valid[tm]){
        #pragma unroll
        for (int j = 0; j < 4; ++j){
          float y = acc[tm][t][j];
          Y[(size_t)((tile0 + tm)*16 + g*4 + j)*N + c] = (unsigned short)f2b(y);
          ys += y; yq += y*y;
        }
      }
    }
    ys += __shfl_xor(ys, 16); ys += __shfl_xor(ys, 32);
    yq += __shfl_xor(yq, 16); yq += __shfl_xor(yq, 32);
    if (g == 0 && valid[0]){
      atomicAdd(&red[c], ys);
      atomicAdd(&red[N+c], yq);
    }
  }
  __syncthreads();
  float* dstAcc = statsAcc + (size_t)(blockIdx.x & (SREP-1)) * (2*N);
  for (int i = tid; i < 2*N; i += 512) atomicAdd(&dstAcc[i], red[i]);
}

// ---------- final output: out = relu(bn(Y)), f32 (N=64), grid-stride ----------
__global__ __launch_bounds__(256) void k_final(const unsigned short* __restrict__ Y,
    const float* __restrict__ st, const float* __restrict__ gam,
    const float* __restrict__ bet, float* __restrict__ out){
  __shared__ float2 absh[64];
  compute_ab<64>(st, gam, bet, absh);
  __syncthreads();
  for (int i = blockIdx.x*256 + threadIdx.x; i < NN*32; i += gridDim.x*256){
    unsigned v = ((const unsigned*)Y)[i];
    int c = (i & 31)*2;
    float2 p0 = absh[c], p1 = absh[c+1];
    float o0 = fmaxf(fmaf(lof(v), p0.x, p0.y), 0.f);
    float o1 = fmaxf(fmaf(hif(v), p1.x, p1.y), 0.f);
    ((float2*)out)[i] = make_float2(o0, o1);
  }
}

extern "C" void kernel_launch(void* const* d_in, const int* in_sizes, int n_in,
                              void* d_out, int out_size, void* d_ws, size_t ws_size,
                              hipStream_t stream) {
  const float* features = (const float*)d_in[0];
  const int* src = (const int*)d_in[1];
  const int* dst = (const int*)d_in[2];
  const float *Wp[6], *gp[6], *bep[6];
  for (int l = 0; l < 3; ++l){
    int base = 3 + 8*l;
    Wp[2*l]    = (const float*)d_in[base+0];
    gp[2*l]    = (const float*)d_in[base+2];
    bep[2*l]   = (const float*)d_in[base+3];
    Wp[2*l+1]  = (const float*)d_in[base+4];
    gp[2*l+1]  = (const float*)d_in[base+6];
    bep[2*l+1] = (const float*)d_in[base+7];
  }

  size_t off = 0;
  char* base = (char*)d_ws;
  auto carve = [&](size_t bytes)->char* {
    char* q = base + off; off += (bytes + 255) & ~(size_t)255; return q;
  };
  // zero-init region: deg + total + 6 replicated stats buffers (contiguous)
  int* deg   = (int*)carve((size_t)NN*4);
  int* total = (int*)carve(4);
  float* stats[6];
  for (int i = 0; i < 6; ++i) stats[i] = (float*)carve((size_t)SREP*256*4);
  size_t zbytes = (size_t)(base + off - (char*)deg);   // multiple of 256

  int* row_off = (int*)carve((size_t)NN*4);
  int* cur     = (int*)carve((size_t)NN*4);
  int* col     = (int*)carve((size_t)(NE + 3*NN)*4);   // padded CSR
  unsigned short* wt[6];
  for (int i = 0; i < 6; ++i) wt[i] = (unsigned short*)carve(128*128*2);
  unsigned short* H0 = (unsigned short*)carve((size_t)(NN+1)*128*2);
  unsigned short* X  = (unsigned short*)carve((size_t)(NN+1)*128*2);
  unsigned short* Y1 = (unsigned short*)carve((size_t)(NN+1)*128*2);
  unsigned short* Y2 = (unsigned short*)carve((size_t)(NN+1)*128*2);

  // fast zero of deg+total+stats
  int zn4 = (int)(zbytes >> 4);
  k_zero<<<(zn4 + 255)/256, 256, 0, stream>>>((uint4v*)deg, zn4);

  W6 jb;
  for (int i = 0; i < 6; ++i){ jb.w[i] = Wp[i]; jb.o[i] = wt[i]; }
  k_pre<<<8898, 256, 0, stream>>>(features, H0, dst, deg, jb);
  k_offsets<<<(NN+255)/256, 256, 0, stream>>>(deg, row_off, cur, col, total);
  k_fill<<<(NE+255)/256, 256, 0, stream>>>(src, dst, cur, col, NE);

  const int agg_grid = 6250;           // 6250 blocks x 4 waves x 2 nodes = 50000
  const int g2_grid = (3125 + 7)/8;    // 391 (CS=2, 8 tiles/block)
  const int g1_grid = (3125 + 15)/16;  // 196 (CS=1, 16 tiles/block)

  // ---- layer 0 ----
  k_agg<false><<<agg_grid, 256, 0, stream>>>(H0, nullptr, nullptr, nullptr, row_off, deg, col, X);
  k_gemm<4,4,2,false><<<g2_grid, 512, 0, stream>>>(X, wt[0], nullptr, nullptr, nullptr, Y1, stats[0]);
  k_gemm<4,4,2,true ><<<g2_grid, 512, 0, stream>>>(Y1, wt[1], stats[0], gp[0], bep[0], Y2, stats[1]);
  // ---- layer 1 ----
  k_agg<true ><<<agg_grid, 256, 0, stream>>>(Y2, stats[1], gp[1], bep[1], row_off, deg, col, X);
  k_gemm<4,4,2,false><<<g2_grid, 512, 0, stream>>>(X, wt[2], nullptr, nullptr, nullptr, Y1, stats[2]);
  k_gemm<4,4,2,true ><<<g2_grid, 512, 0, stream>>>(Y1, wt[3], stats[2], gp[2], bep[2], Y2, stats[3]);
  // ---- layer 2 ----
  k_agg<true ><<<agg_grid, 256, 0, stream>>>(Y2, stats[3], gp[3], bep[3], row_off, deg, col, X);
  k_gemm<4,4,1,false><<<g1_grid, 512, 0, stream>>>(X, wt[4], nullptr, nullptr, nullptr, Y1, stats[4]);
  k_gemm<2,4,1,true ><<<g1_grid, 512, 0, stream>>>(Y1, wt[5], stats[4], gp[4], bep[4], Y2, stats[5]);
  k_final<<<782, 256, 0, stream>>>(Y2, stats[5], gp[5], bep[5], (float*)d_out);
}

// Round 19
// 242.878 us; speedup vs baseline: 1.9452x; 1.0787x over previous
//
#include <hip/hip_runtime.h>

#define NN 50000
#define NE 600000
#define SREP 32

typedef __attribute__((ext_vector_type(8))) short short8;
typedef __attribute__((ext_vector_type(4))) float f32x4;
typedef __attribute__((ext_vector_type(4))) unsigned uint4v;

__device__ __forceinline__ float bf2f(unsigned short u){
  union { unsigned int i; float f; } c; c.i = ((unsigned int)u) << 16; return c.f;
}
__device__ __forceinline__ float lof(unsigned v){
  union { unsigned int i; float f; } c; c.i = v << 16; return c.f;
}
__device__ __forceinline__ float hif(unsigned v){
  union { unsigned int i; float f; } c; c.i = v & 0xFFFF0000u; return c.f;
}
__device__ __forceinline__ unsigned short f2b(float f){
  union { float f; unsigned int i; } c; c.f = f;
  unsigned int i = c.i;
  return (unsigned short)((i + 0x7FFFu + ((i >> 16) & 1u)) >> 16);
}

// ---------- fast workspace zero ----------
__global__ __launch_bounds__(256) void k_zero(uint4v* __restrict__ p, int n4){
  int i = blockIdx.x*256 + threadIdx.x;
  if (i < n4) p[i] = (uint4v){0,0,0,0};
}

// ---------- per-block BN coefficient computation from replicated stats ----------
template<int N>
__device__ __forceinline__ void compute_ab(const float* __restrict__ st,
    const float* __restrict__ gam, const float* __restrict__ bet, float2* absh){
  int tid = threadIdx.x;
  if (tid < N){
    float s = 0.f, q = 0.f;
    #pragma unroll
    for (int r = 0; r < SREP; ++r){
      s += st[r*2*N + tid];
      q += st[r*2*N + N + tid];
    }
    float mu = s * (1.f/(float)NN);
    float var = fmaxf(q * (1.f/(float)NN) - mu*mu, 0.f);
    float a = gam[tid] * rsqrtf(var + 1e-5f);
    absh[tid] = make_float2(a, bet[tid] - mu*a);
  }
}

// ---------- fused preprocessing: cvt | hist | wconv ----------
struct W6 { const float* w[6]; unsigned short* o[6]; };
__global__ __launch_bounds__(256) void k_pre(const float* __restrict__ features,
    unsigned short* __restrict__ H0, const int* __restrict__ dst,
    int* __restrict__ deg, W6 jb){
  int b = blockIdx.x, tid = threadIdx.x;
  if (b < 6250){                       // cvt: NN*128 floats as float4 -> bf16x4
    int i = b*256 + tid;               // i < NN*32 exactly
    float4 v = ((const float4*)features)[i];
    uint2 o;
    o.x = (unsigned)f2b(v.x) | ((unsigned)f2b(v.y) << 16);
    o.y = (unsigned)f2b(v.z) | ((unsigned)f2b(v.w) << 16);
    ((uint2*)H0)[i] = o;
  } else if (b < 6250 + 2344){         // hist
    int i = (b - 6250)*256 + tid;
    if (i < NE) atomicAdd(&deg[dst[i]], 1);
  } else {                             // weight transpose+convert, 6 jobs
    int i = (b - 8594)*256 + tid;
    if (i < 77824){
      int job, base, K, N;
      if (i < 65536){ job = i >> 14; base = job << 14; K = 128; N = 128; }
      else if (i < 73728){ job = 4; base = 65536; K = 128; N = 64; }
      else { job = 5; base = 73728; K = 64; N = 64; }
      int t = i - base;
      int k = t & (K-1);
      int n = t / K;
      jb.o[job][t] = f2b(jb.w[job][k*N + n]);
    }
  }
}

// ---------- CSR offsets (block-local scan over PADDED degrees + pad-slot fill) ----------
__global__ void k_offsets(const int* __restrict__ deg, int* __restrict__ row_off,
                          int* __restrict__ cur, int* __restrict__ col,
                          int* __restrict__ total){
  __shared__ int ws[4];
  __shared__ int wbase[4];
  int tid = threadIdx.x, lane = tid & 63, wid = tid >> 6;
  int i = blockIdx.x*256 + tid;
  int v = (i < NN) ? deg[i] : 0;
  int vp = (v + 3) & ~3;               // padded degree
  int x = vp;
  #pragma unroll
  for (int o = 1; o < 64; o <<= 1){
    int t = __shfl_up(x, o);
    if (lane >= o) x += t;
  }
  if (lane == 63) ws[wid] = x;
  __syncthreads();
  if (tid == 0){
    int s0 = ws[0], s1 = ws[1], s2 = ws[2], s3 = ws[3];
    int b = atomicAdd(total, s0+s1+s2+s3);
    wbase[0] = b; wbase[1] = b+s0; wbase[2] = b+s0+s1; wbase[3] = b+s0+s1+s2;
  }
  __syncthreads();
  if (i < NN){
    int excl = wbase[wid] + x - vp;
    row_off[i] = excl;
    cur[i] = excl;
    for (int t = v; t < vp; ++t) col[excl + t] = NN;   // pad -> zero dummy node
  }
}

__global__ void k_fill(const int* __restrict__ src, const int* __restrict__ dst,
                       int* __restrict__ cur, int* __restrict__ col, int e){
  int i = blockIdx.x*blockDim.x + threadIdx.x;
  if (i >= e) return;
  int d = dst[i];
  int pos = atomicAdd(&cur[d], 1);
  col[pos] = src[i];
}

// ---------- aggregation: x = act(h) + mean(act(h[neigh])) ----------
// TWO nodes per wave (one per 32-lane half). Within a half: p=hl&15 covers the
// 128 cols (uint4/lane), qq=hl>>4 picks odd/even edge. Per batch, 4 steps x 2
// quarters = 8 row-gathers in flight per half (16/wave). Shuffles source only
// within the executing half -> safe under divergence (round-4 lesson).
// Pad edges gather the zero dummy row; with APPLY each contributes relu(b_c),
// subtracted analytically. Invalid (beyond-steps) slots gather the dummy row
// but are excluded from ACC.
template<bool APPLY>
__global__ __launch_bounds__(256) void k_agg(const unsigned short* __restrict__ H,
    const float* __restrict__ st, const float* __restrict__ gam,
    const float* __restrict__ bet, const int* __restrict__ row_off,
    const int* __restrict__ deg, const int* __restrict__ col,
    unsigned short* __restrict__ X){
  __shared__ float2 absh[128];
  if (APPLY){ compute_ab<128>(st, gam, bet, absh); __syncthreads(); }
  int lane = threadIdx.x & 63;
  int wave = threadIdx.x >> 6;
  int half = lane >> 5, hl = lane & 31;
  int p = hl & 15, qq = hl >> 4;
  float ac[8], bc[8];
  if (APPLY){
    #pragma unroll
    for (int e = 0; e < 8; ++e){ float2 t = absh[p*8 + e]; ac[e] = t.x; bc[e] = t.y; }
  }
  const uint4* hp4 = (const uint4*)H;
  int P = blockIdx.x*4 + wave;         // 0..24999 (grid 6250)
  int node = 2*P + half;               // < 50000 exactly
  int beg = row_off[node];
  int d = deg[node];
  int dp = (d + 3) & ~3;
  float s[8];
  #pragma unroll
  for (int e = 0; e < 8; ++e) s[e] = 0.f;
  auto ACC = [&](uint4 v){
    float x;
    x = lof(v.x); if (APPLY) x = fmaxf(fmaf(x,ac[0],bc[0]),0.f); s[0] += x;
    x = hif(v.x); if (APPLY) x = fmaxf(fmaf(x,ac[1],bc[1]),0.f); s[1] += x;
    x = lof(v.y); if (APPLY) x = fmaxf(fmaf(x,ac[2],bc[2]),0.f); s[2] += x;
    x = hif(v.y); if (APPLY) x = fmaxf(fmaf(x,ac[3],bc[3]),0.f); s[3] += x;
    x = lof(v.z); if (APPLY) x = fmaxf(fmaf(x,ac[4],bc[4]),0.f); s[4] += x;
    x = hif(v.z); if (APPLY) x = fmaxf(fmaf(x,ac[5],bc[5]),0.f); s[5] += x;
    x = lof(v.w); if (APPLY) x = fmaxf(fmaf(x,ac[6],bc[6]),0.f); s[6] += x;
    x = hif(v.w); if (APPLY) x = fmaxf(fmaf(x,ac[7],bc[7]),0.f); s[7] += x;
  };
  for (int base = 0; base < dp; base += 32){
    int wdp = dp - base; if (wdp > 32) wdp = 32;     // multiple of 4
    int cvs = (hl < wdp) ? col[beg + base + hl] : NN;
    int steps = wdp >> 1;                            // edges per quarter
    for (int s0 = 0; s0 < steps; s0 += 4){
      int idx[4], val[4];
      #pragma unroll
      for (int u = 0; u < 4; ++u){
        int stp = s0 + u;
        int v = (stp < steps);
        int e = v ? (2*stp + qq) : 0;
        int ix = __shfl(cvs, 32*half + e);           // in-half source, all-active
        idx[u] = v ? ix : NN;
        val[u] = v;
      }
      uint4 vv[4];
      #pragma unroll
      for (int u = 0; u < 4; ++u) vv[u] = hp4[(size_t)idx[u]*16 + p];
      #pragma unroll
      for (int u = 0; u < 4; ++u) if (val[u]) ACC(vv[u]);
    }
  }
  #pragma unroll
  for (int e = 0; e < 8; ++e) s[e] += __shfl_xor(s[e], 16);   // combine qq pair (stays in half)
  if (qq == 0){
    uint4 hv = hp4[(size_t)node*16 + p];
    float inv = 1.f / (float)(d > 0 ? d : 1);
    float npad = (float)(dp - d);
    float h[8] = {lof(hv.x),hif(hv.x),lof(hv.y),hif(hv.y),
                  lof(hv.z),hif(hv.z),lof(hv.w),hif(hv.w)};
    unsigned w[4];
    #pragma unroll
    for (int u = 0; u < 4; ++u){
      float x0 = h[2*u], x1 = h[2*u+1];
      float s0 = s[2*u], s1 = s[2*u+1];
      if (APPLY){
        x0 = fmaxf(fmaf(x0,ac[2*u],bc[2*u]),0.f);
        x1 = fmaxf(fmaf(x1,ac[2*u+1],bc[2*u+1]),0.f);
        s0 -= npad * fmaxf(bc[2*u], 0.f);     // remove pad-edge relu(b) terms
        s1 -= npad * fmaxf(bc[2*u+1], 0.f);
      }
      x0 += s0*inv;
      x1 += s1*inv;
      w[u] = (unsigned)f2b(x0) | ((unsigned)f2b(x1) << 16);
    }
    ((uint4*)X)[(size_t)node*16 + p] = make_uint4(w[0], w[1], w[2], w[3]);
  }
}

// ---------- GEMM: TM 16-row tiles per wave, column-split CS; B reuse = TM ----------
// Y[NN][N] = act(A)[NN][K] @ BT[N][K]^T, fused BN stats; APPLY = BN+relu on A-load.
// wave w: row-group = w/CS (owns TM consecutive tiles), col-half ch = w%CS.
// Each B fragment feeds TM MFMAs; TM independent A-chains hide load latency
// (r17 finding: B not held resident; r18: TM=2 gave -28us).
template<int KSTEPS, int NT, int CS, int TM, int NTHR, bool APPLY>
__global__ __launch_bounds__(NTHR) void k_gemm(const unsigned short* __restrict__ A,
    const unsigned short* __restrict__ BT,
    const float* __restrict__ stIn, const float* __restrict__ gam,
    const float* __restrict__ bet,
    unsigned short* __restrict__ Y, float* __restrict__ statsAcc){
  constexpr int K = KSTEPS*32;
  constexpr int N = CS*NT*16;
  constexpr int TILES = NN/16;         // 3125
  constexpr int WAVES = NTHR/64;
  constexpr int TPB = (WAVES/CS)*TM;
  __shared__ float red[2*N];
  __shared__ float2 absh[K];
  if (APPLY) compute_ab<K>(stIn, gam, bet, absh);
  int tid = threadIdx.x;
  int lane = tid & 63, w = tid >> 6;
  int r = lane & 15, g = lane >> 4;
  int tile0 = blockIdx.x*TPB + (w / CS)*TM;
  int ch = w % CS;
  bool valid[TM];
  #pragma unroll
  for (int tm = 0; tm < TM; ++tm) valid[tm] = (tile0 + tm < TILES);
  short8 af[TM][KSTEPS];
  #pragma unroll
  for (int tm = 0; tm < TM; ++tm){
    int arow = valid[tm] ? (tile0 + tm)*16 + r : 0;
    #pragma unroll
    for (int kk = 0; kk < KSTEPS; ++kk)
      af[tm][kk] = *(const short8*)(A + (size_t)arow*K + kk*32 + g*8);
  }
  for (int i = tid; i < 2*N; i += NTHR) red[i] = 0.f;
  __syncthreads();                     // red zeroed + absh ready
  if (APPLY){
    #pragma unroll
    for (int tm = 0; tm < TM; ++tm)
      #pragma unroll
      for (int kk = 0; kk < KSTEPS; ++kk){
        #pragma unroll
        for (int j = 0; j < 8; ++j){
          float2 pab = absh[kk*32 + g*8 + j];
          float v = fmaxf(fmaf(bf2f((unsigned short)af[tm][kk][j]), pab.x, pab.y), 0.f);
          af[tm][kk][j] = (short)f2b(v);
        }
      }
  }
  f32x4 acc[TM][NT];
  #pragma unroll
  for (int tm = 0; tm < TM; ++tm)
    #pragma unroll
    for (int t = 0; t < NT; ++t) acc[tm][t] = (f32x4){0.f,0.f,0.f,0.f};
  #pragma unroll
  for (int kk = 0; kk < KSTEPS; ++kk)
    #pragma unroll
    for (int t = 0; t < NT; ++t){
      short8 b = *(const short8*)(BT + (size_t)(ch*NT*16 + t*16 + r)*K + kk*32 + g*8);
      #pragma unroll
      for (int tm = 0; tm < TM; ++tm)
        acc[tm][t] = __builtin_amdgcn_mfma_f32_16x16x32_bf16(af[tm][kk], b, acc[tm][t], 0, 0, 0);
    }
  #pragma unroll
  for (int t = 0; t < NT; ++t){
    int c = ch*NT*16 + t*16 + r;
    float ys = 0.f, yq = 0.f;
    #pragma unroll
    for (int tm = 0; tm < TM; ++tm){
      if (valid[tm]){
        #pragma unroll
        for (int j = 0; j < 4; ++j){
          float y = acc[tm][t][j];
          Y[(size_t)((tile0 + tm)*16 + g*4 + j)*N + c] = (unsigned short)f2b(y);
          ys += y; yq += y*y;
        }
      }
    }
    ys += __shfl_xor(ys, 16); ys += __shfl_xor(ys, 32);
    yq += __shfl_xor(yq, 16); yq += __shfl_xor(yq, 32);
    if (g == 0 && valid[0]){
      atomicAdd(&red[c], ys);
      atomicAdd(&red[N+c], yq);
    }
  }
  __syncthreads();
  float* dstAcc = statsAcc + (size_t)(blockIdx.x & (SREP-1)) * (2*N);
  for (int i = tid; i < 2*N; i += NTHR) atomicAdd(&dstAcc[i], red[i]);
}

// ---------- final output: out = relu(bn(Y)), f32 (N=64), grid-stride ----------
__global__ __launch_bounds__(256) void k_final(const unsigned short* __restrict__ Y,
    const float* __restrict__ st, const float* __restrict__ gam,
    const float* __restrict__ bet, float* __restrict__ out){
  __shared__ float2 absh[64];
  compute_ab<64>(st, gam, bet, absh);
  __syncthreads();
  for (int i = blockIdx.x*256 + threadIdx.x; i < NN*32; i += gridDim.x*256){
    unsigned v = ((const unsigned*)Y)[i];
    int c = (i & 31)*2;
    float2 p0 = absh[c], p1 = absh[c+1];
    float o0 = fmaxf(fmaf(lof(v), p0.x, p0.y), 0.f);
    float o1 = fmaxf(fmaf(hif(v), p1.x, p1.y), 0.f);
    ((float2*)out)[i] = make_float2(o0, o1);
  }
}

extern "C" void kernel_launch(void* const* d_in, const int* in_sizes, int n_in,
                              void* d_out, int out_size, void* d_ws, size_t ws_size,
                              hipStream_t stream) {
  const float* features = (const float*)d_in[0];
  const int* src = (const int*)d_in[1];
  const int* dst = (const int*)d_in[2];
  const float *Wp[6], *gp[6], *bep[6];
  for (int l = 0; l < 3; ++l){
    int base = 3 + 8*l;
    Wp[2*l]    = (const float*)d_in[base+0];
    gp[2*l]    = (const float*)d_in[base+2];
    bep[2*l]   = (const float*)d_in[base+3];
    Wp[2*l+1]  = (const float*)d_in[base+4];
    gp[2*l+1]  = (const float*)d_in[base+6];
    bep[2*l+1] = (const float*)d_in[base+7];
  }

  size_t off = 0;
  char* base = (char*)d_ws;
  auto carve = [&](size_t bytes)->char* {
    char* q = base + off; off += (bytes + 255) & ~(size_t)255; return q;
  };
  // zero-init region: deg + total + 6 replicated stats buffers (contiguous)
  int* deg   = (int*)carve((size_t)NN*4);
  int* total = (int*)carve(4);
  float* stats[6];
  for (int i = 0; i < 6; ++i) stats[i] = (float*)carve((size_t)SREP*256*4);
  size_t zbytes = (size_t)(base + off - (char*)deg);   // multiple of 256

  int* row_off = (int*)carve((size_t)NN*4);
  int* cur     = (int*)carve((size_t)NN*4);
  int* col     = (int*)carve((size_t)(NE + 3*NN)*4);   // padded CSR
  unsigned short* wt[6];
  for (int i = 0; i < 6; ++i) wt[i] = (unsigned short*)carve(128*128*2);
  unsigned short* H0 = (unsigned short*)carve((size_t)(NN+1)*128*2);
  unsigned short* X  = (unsigned short*)carve((size_t)(NN+1)*128*2);
  unsigned short* Y1 = (unsigned short*)carve((size_t)(NN+1)*128*2);
  unsigned short* Y2 = (unsigned short*)carve((size_t)(NN+1)*128*2);

  // fast zero of deg+total+stats
  int zn4 = (int)(zbytes >> 4);
  k_zero<<<(zn4 + 255)/256, 256, 0, stream>>>((uint4v*)deg, zn4);

  W6 jb;
  for (int i = 0; i < 6; ++i){ jb.w[i] = Wp[i]; jb.o[i] = wt[i]; }
  k_pre<<<8898, 256, 0, stream>>>(features, H0, dst, deg, jb);
  k_offsets<<<(NN+255)/256, 256, 0, stream>>>(deg, row_off, cur, col, total);
  k_fill<<<(NE+255)/256, 256, 0, stream>>>(src, dst, cur, col, NE);

  const int agg_grid = 6250;           // 6250 blocks x 4 waves x 2 nodes = 50000
  const int g2_grid = (3125 + 7)/8;    // 391: CS=2, TM=4, 256 threads -> TPB=8
  const int g1_grid = (3125 + 15)/16;  // 196: CS=1, TM=2, 512 threads -> TPB=16

  // ---- layer 0 ----
  k_agg<false><<<agg_grid, 256, 0, stream>>>(H0, nullptr, nullptr, nullptr, row_off, deg, col, X);
  k_gemm<4,4,2,4,256,false><<<g2_grid, 256, 0, stream>>>(X, wt[0], nullptr, nullptr, nullptr, Y1, stats[0]);
  k_gemm<4,4,2,4,256,true ><<<g2_grid, 256, 0, stream>>>(Y1, wt[1], stats[0], gp[0], bep[0], Y2, stats[1]);
  // ---- layer 1 ----
  k_agg<true ><<<agg_grid, 256, 0, stream>>>(Y2, stats[1], gp[1], bep[1], row_off, deg, col, X);
  k_gemm<4,4,2,4,256,false><<<g2_grid, 256, 0, stream>>>(X, wt[2], nullptr, nullptr, nullptr, Y1, stats[2]);
  k_gemm<4,4,2,4,256,true ><<<g2_grid, 256, 0, stream>>>(Y1, wt[3], stats[2], gp[2], bep[2], Y2, stats[3]);
  // ---- layer 2 ----
  k_agg<true ><<<agg_grid, 256, 0, stream>>>(Y2, stats[3], gp[3], bep[3], row_off, deg, col, X);
  k_gemm<4,4,1,2,512,false><<<g1_grid, 512, 0, stream>>>(X, wt[4], nullptr, nullptr, nullptr, Y1, stats[4]);
  k_gemm<2,4,1,2,512,true ><<<g1_grid, 512, 0, stream>>>(Y1, wt[5], stats[4], gp[4], bep[4], Y2, stats[5]);
  k_final<<<782, 256, 0, stream>>>(Y2, stats[5], gp[5], bep[5], (float*)d_out);
}

// Round 20
// 241.103 us; speedup vs baseline: 1.9595x; 1.0074x over previous
//
#include <hip/hip_runtime.h>

#define NN 50000
#define NE 600000
#define SREP 32

typedef __attribute__((ext_vector_type(8))) short short8;
typedef __attribute__((ext_vector_type(4))) float f32x4;
typedef __attribute__((ext_vector_type(4))) unsigned uint4v;

__device__ __forceinline__ float bf2f(unsigned short u){
  union { unsigned int i; float f; } c; c.i = ((unsigned int)u) << 16; return c.f;
}
__device__ __forceinline__ float lof(unsigned v){
  union { unsigned int i; float f; } c; c.i = v << 16; return c.f;
}
__device__ __forceinline__ float hif(unsigned v){
  union { unsigned int i; float f; } c; c.i = v & 0xFFFF0000u; return c.f;
}
__device__ __forceinline__ unsigned short f2b(float f){
  union { float f; unsigned int i; } c; c.f = f;
  unsigned int i = c.i;
  return (unsigned short)((i + 0x7FFFu + ((i >> 16) & 1u)) >> 16);
}

// ---------- fast workspace zero ----------
__global__ __launch_bounds__(256) void k_zero(uint4v* __restrict__ p, int n4){
  int i = blockIdx.x*256 + threadIdx.x;
  if (i < n4) p[i] = (uint4v){0,0,0,0};
}

// ---------- per-block BN coefficient computation from replicated stats ----------
template<int N>
__device__ __forceinline__ void compute_ab(const float* __restrict__ st,
    const float* __restrict__ gam, const float* __restrict__ bet, float2* absh){
  int tid = threadIdx.x;
  if (tid < N){
    float s = 0.f, q = 0.f;
    #pragma unroll
    for (int r = 0; r < SREP; ++r){
      s += st[r*2*N + tid];
      q += st[r*2*N + N + tid];
    }
    float mu = s * (1.f/(float)NN);
    float var = fmaxf(q * (1.f/(float)NN) - mu*mu, 0.f);
    float a = gam[tid] * rsqrtf(var + 1e-5f);
    absh[tid] = make_float2(a, bet[tid] - mu*a);
  }
}

// ---------- fused preprocessing: cvt | hist | wconv ----------
struct W6 { const float* w[6]; unsigned short* o[6]; };
__global__ __launch_bounds__(256) void k_pre(const float* __restrict__ features,
    unsigned short* __restrict__ H0, const int* __restrict__ dst,
    int* __restrict__ deg, W6 jb){
  int b = blockIdx.x, tid = threadIdx.x;
  if (b < 6250){                       // cvt: NN*128 floats as float4 -> bf16x4
    int i = b*256 + tid;               // i < NN*32 exactly
    float4 v = ((const float4*)features)[i];
    uint2 o;
    o.x = (unsigned)f2b(v.x) | ((unsigned)f2b(v.y) << 16);
    o.y = (unsigned)f2b(v.z) | ((unsigned)f2b(v.w) << 16);
    ((uint2*)H0)[i] = o;
  } else if (b < 6250 + 2344){         // hist
    int i = (b - 6250)*256 + tid;
    if (i < NE) atomicAdd(&deg[dst[i]], 1);
  } else {                             // weight transpose+convert, 6 jobs
    int i = (b - 8594)*256 + tid;
    if (i < 77824){
      int job, base, K, N;
      if (i < 65536){ job = i >> 14; base = job << 14; K = 128; N = 128; }
      else if (i < 73728){ job = 4; base = 65536; K = 128; N = 64; }
      else { job = 5; base = 73728; K = 64; N = 64; }
      int t = i - base;
      int k = t & (K-1);
      int n = t / K;
      jb.o[job][t] = f2b(jb.w[job][k*N + n]);
    }
  }
}

// ---------- CSR offsets (block-local scan over PADDED degrees + pad-slot fill) ----------
__global__ void k_offsets(const int* __restrict__ deg, int* __restrict__ row_off,
                          int* __restrict__ cur, int* __restrict__ col,
                          int* __restrict__ total){
  __shared__ int ws[4];
  __shared__ int wbase[4];
  int tid = threadIdx.x, lane = tid & 63, wid = tid >> 6;
  int i = blockIdx.x*256 + tid;
  int v = (i < NN) ? deg[i] : 0;
  int vp = (v + 3) & ~3;               // padded degree
  int x = vp;
  #pragma unroll
  for (int o = 1; o < 64; o <<= 1){
    int t = __shfl_up(x, o);
    if (lane >= o) x += t;
  }
  if (lane == 63) ws[wid] = x;
  __syncthreads();
  if (tid == 0){
    int s0 = ws[0], s1 = ws[1], s2 = ws[2], s3 = ws[3];
    int b = atomicAdd(total, s0+s1+s2+s3);
    wbase[0] = b; wbase[1] = b+s0; wbase[2] = b+s0+s1; wbase[3] = b+s0+s1+s2;
  }
  __syncthreads();
  if (i < NN){
    int excl = wbase[wid] + x - vp;
    row_off[i] = excl;
    cur[i] = excl;
    for (int t = v; t < vp; ++t) col[excl + t] = NN;   // pad -> zero dummy node
  }
}

__global__ void k_fill(const int* __restrict__ src, const int* __restrict__ dst,
                       int* __restrict__ cur, int* __restrict__ col, int e){
  int i = blockIdx.x*blockDim.x + threadIdx.x;
  if (i >= e) return;
  int d = dst[i];
  int pos = atomicAdd(&cur[d], 1);
  col[pos] = src[i];
}

// ---------- aggregation: x = act(h) + mean(act(h[neigh])) ----------
// TWO nodes per wave (one per 32-lane half). Within a half: p=hl&15 covers the
// 128 cols (uint4/lane), qq=hl>>4 picks odd/even edge. Per batch, 4 steps x 2
// quarters = 8 row-gathers in flight per half (16/wave). Shuffles source only
// within the executing half -> safe under divergence (round-4 lesson).
// Pad edges gather the zero dummy row; with APPLY each contributes relu(b_c),
// subtracted analytically. Invalid (beyond-steps) slots gather the dummy row
// but are excluded from ACC.
template<bool APPLY>
__global__ __launch_bounds__(256) void k_agg(const unsigned short* __restrict__ H,
    const float* __restrict__ st, const float* __restrict__ gam,
    const float* __restrict__ bet, const int* __restrict__ row_off,
    const int* __restrict__ deg, const int* __restrict__ col,
    unsigned short* __restrict__ X){
  __shared__ float2 absh[128];
  if (APPLY){ compute_ab<128>(st, gam, bet, absh); __syncthreads(); }
  int lane = threadIdx.x & 63;
  int wave = threadIdx.x >> 6;
  int half = lane >> 5, hl = lane & 31;
  int p = hl & 15, qq = hl >> 4;
  float ac[8], bc[8];
  if (APPLY){
    #pragma unroll
    for (int e = 0; e < 8; ++e){ float2 t = absh[p*8 + e]; ac[e] = t.x; bc[e] = t.y; }
  }
  const uint4* hp4 = (const uint4*)H;
  int P = blockIdx.x*4 + wave;         // 0..24999 (grid 6250)
  int node = 2*P + half;               // < 50000 exactly
  int beg = row_off[node];
  int d = deg[node];
  int dp = (d + 3) & ~3;
  float s[8];
  #pragma unroll
  for (int e = 0; e < 8; ++e) s[e] = 0.f;
  auto ACC = [&](uint4 v){
    float x;
    x = lof(v.x); if (APPLY) x = fmaxf(fmaf(x,ac[0],bc[0]),0.f); s[0] += x;
    x = hif(v.x); if (APPLY) x = fmaxf(fmaf(x,ac[1],bc[1]),0.f); s[1] += x;
    x = lof(v.y); if (APPLY) x = fmaxf(fmaf(x,ac[2],bc[2]),0.f); s[2] += x;
    x = hif(v.y); if (APPLY) x = fmaxf(fmaf(x,ac[3],bc[3]),0.f); s[3] += x;
    x = lof(v.z); if (APPLY) x = fmaxf(fmaf(x,ac[4],bc[4]),0.f); s[4] += x;
    x = hif(v.z); if (APPLY) x = fmaxf(fmaf(x,ac[5],bc[5]),0.f); s[5] += x;
    x = lof(v.w); if (APPLY) x = fmaxf(fmaf(x,ac[6],bc[6]),0.f); s[6] += x;
    x = hif(v.w); if (APPLY) x = fmaxf(fmaf(x,ac[7],bc[7]),0.f); s[7] += x;
  };
  for (int base = 0; base < dp; base += 32){
    int wdp = dp - base; if (wdp > 32) wdp = 32;     // multiple of 4
    int cvs = (hl < wdp) ? col[beg + base + hl] : NN;
    int steps = wdp >> 1;                            // edges per quarter
    for (int s0 = 0; s0 < steps; s0 += 4){
      int idx[4], val[4];
      #pragma unroll
      for (int u = 0; u < 4; ++u){
        int stp = s0 + u;
        int v = (stp < steps);
        int e = v ? (2*stp + qq) : 0;
        int ix = __shfl(cvs, 32*half + e);           // in-half source, all-active
        idx[u] = v ? ix : NN;
        val[u] = v;
      }
      uint4 vv[4];
      #pragma unroll
      for (int u = 0; u < 4; ++u) vv[u] = hp4[(size_t)idx[u]*16 + p];
      #pragma unroll
      for (int u = 0; u < 4; ++u) if (val[u]) ACC(vv[u]);
    }
  }
  #pragma unroll
  for (int e = 0; e < 8; ++e) s[e] += __shfl_xor(s[e], 16);   // combine qq pair (stays in half)
  if (qq == 0){
    uint4 hv = hp4[(size_t)node*16 + p];
    float inv = 1.f / (float)(d > 0 ? d : 1);
    float npad = (float)(dp - d);
    float h[8] = {lof(hv.x),hif(hv.x),lof(hv.y),hif(hv.y),
                  lof(hv.z),hif(hv.z),lof(hv.w),hif(hv.w)};
    unsigned w[4];
    #pragma unroll
    for (int u = 0; u < 4; ++u){
      float x0 = h[2*u], x1 = h[2*u+1];
      float s0 = s[2*u], s1 = s[2*u+1];
      if (APPLY){
        x0 = fmaxf(fmaf(x0,ac[2*u],bc[2*u]),0.f);
        x1 = fmaxf(fmaf(x1,ac[2*u+1],bc[2*u+1]),0.f);
        s0 -= npad * fmaxf(bc[2*u], 0.f);     // remove pad-edge relu(b) terms
        s1 -= npad * fmaxf(bc[2*u+1], 0.f);
      }
      x0 += s0*inv;
      x1 += s1*inv;
      w[u] = (unsigned)f2b(x0) | ((unsigned)f2b(x1) << 16);
    }
    ((uint4*)X)[(size_t)node*16 + p] = make_uint4(w[0], w[1], w[2], w[3]);
  }
}

// ---------- GEMM: TM 16-row tiles per wave, column-split CS; B reuse = TM ----------
// Y[NN][N] = act(A)[NN][K] @ BT[N][K]^T, fused BN stats; APPLY = BN+relu on A-load.
// wave w: row-group = w/CS (owns TM consecutive tiles), col-half ch = w%CS.
// Each B fragment feeds TM MFMAs; TM independent A-chains hide load latency
// (r17 finding: B not held resident; r18 TM=2: -28us; r19 TM=4: -19us).
template<int KSTEPS, int NT, int CS, int TM, int NTHR, bool APPLY>
__global__ __launch_bounds__(NTHR) void k_gemm(const unsigned short* __restrict__ A,
    const unsigned short* __restrict__ BT,
    const float* __restrict__ stIn, const float* __restrict__ gam,
    const float* __restrict__ bet,
    unsigned short* __restrict__ Y, float* __restrict__ statsAcc){
  constexpr int K = KSTEPS*32;
  constexpr int N = CS*NT*16;
  constexpr int TILES = NN/16;         // 3125
  constexpr int WAVES = NTHR/64;
  constexpr int TPB = (WAVES/CS)*TM;
  __shared__ float red[2*N];
  __shared__ float2 absh[K];
  if (APPLY) compute_ab<K>(stIn, gam, bet, absh);
  int tid = threadIdx.x;
  int lane = tid & 63, w = tid >> 6;
  int r = lane & 15, g = lane >> 4;
  int tile0 = blockIdx.x*TPB + (w / CS)*TM;
  int ch = w % CS;
  bool valid[TM];
  #pragma unroll
  for (int tm = 0; tm < TM; ++tm) valid[tm] = (tile0 + tm < TILES);
  short8 af[TM][KSTEPS];
  #pragma unroll
  for (int tm = 0; tm < TM; ++tm){
    int arow = valid[tm] ? (tile0 + tm)*16 + r : 0;
    #pragma unroll
    for (int kk = 0; kk < KSTEPS; ++kk)
      af[tm][kk] = *(const short8*)(A + (size_t)arow*K + kk*32 + g*8);
  }
  for (int i = tid; i < 2*N; i += NTHR) red[i] = 0.f;
  __syncthreads();                     // red zeroed + absh ready
  if (APPLY){
    #pragma unroll
    for (int tm = 0; tm < TM; ++tm)
      #pragma unroll
      for (int kk = 0; kk < KSTEPS; ++kk){
        #pragma unroll
        for (int j = 0; j < 8; ++j){
          float2 pab = absh[kk*32 + g*8 + j];
          float v = fmaxf(fmaf(bf2f((unsigned short)af[tm][kk][j]), pab.x, pab.y), 0.f);
          af[tm][kk][j] = (short)f2b(v);
        }
      }
  }
  f32x4 acc[TM][NT];
  #pragma unroll
  for (int tm = 0; tm < TM; ++tm)
    #pragma unroll
    for (int t = 0; t < NT; ++t) acc[tm][t] = (f32x4){0.f,0.f,0.f,0.f};
  #pragma unroll
  for (int kk = 0; kk < KSTEPS; ++kk)
    #pragma unroll
    for (int t = 0; t < NT; ++t){
      short8 b = *(const short8*)(BT + (size_t)(ch*NT*16 + t*16 + r)*K + kk*32 + g*8);
      #pragma unroll
      for (int tm = 0; tm < TM; ++tm)
        acc[tm][t] = __builtin_amdgcn_mfma_f32_16x16x32_bf16(af[tm][kk], b, acc[tm][t], 0, 0, 0);
    }
  #pragma unroll
  for (int t = 0; t < NT; ++t){
    int c = ch*NT*16 + t*16 + r;
    float ys = 0.f, yq = 0.f;
    #pragma unroll
    for (int tm = 0; tm < TM; ++tm){
      if (valid[tm]){
        #pragma unroll
        for (int j = 0; j < 4; ++j){
          float y = acc[tm][t][j];
          Y[(size_t)((tile0 + tm)*16 + g*4 + j)*N + c] = (unsigned short)f2b(y);
          ys += y; yq += y*y;
        }
      }
    }
    ys += __shfl_xor(ys, 16); ys += __shfl_xor(ys, 32);
    yq += __shfl_xor(yq, 16); yq += __shfl_xor(yq, 32);
    if (g == 0 && valid[0]){
      atomicAdd(&red[c], ys);
      atomicAdd(&red[N+c], yq);
    }
  }
  __syncthreads();
  float* dstAcc = statsAcc + (size_t)(blockIdx.x & (SREP-1)) * (2*N);
  for (int i = tid; i < 2*N; i += NTHR) atomicAdd(&dstAcc[i], red[i]);
}

// ---------- final output: out = relu(bn(Y)), f32 (N=64), grid-stride ----------
__global__ __launch_bounds__(256) void k_final(const unsigned short* __restrict__ Y,
    const float* __restrict__ st, const float* __restrict__ gam,
    const float* __restrict__ bet, float* __restrict__ out){
  __shared__ float2 absh[64];
  compute_ab<64>(st, gam, bet, absh);
  __syncthreads();
  for (int i = blockIdx.x*256 + threadIdx.x; i < NN*32; i += gridDim.x*256){
    unsigned v = ((const unsigned*)Y)[i];
    int c = (i & 31)*2;
    float2 p0 = absh[c], p1 = absh[c+1];
    float o0 = fmaxf(fmaf(lof(v), p0.x, p0.y), 0.f);
    float o1 = fmaxf(fmaf(hif(v), p1.x, p1.y), 0.f);
    ((float2*)out)[i] = make_float2(o0, o1);
  }
}

extern "C" void kernel_launch(void* const* d_in, const int* in_sizes, int n_in,
                              void* d_out, int out_size, void* d_ws, size_t ws_size,
                              hipStream_t stream) {
  const float* features = (const float*)d_in[0];
  const int* src = (const int*)d_in[1];
  const int* dst = (const int*)d_in[2];
  const float *Wp[6], *gp[6], *bep[6];
  for (int l = 0; l < 3; ++l){
    int base = 3 + 8*l;
    Wp[2*l]    = (const float*)d_in[base+0];
    gp[2*l]    = (const float*)d_in[base+2];
    bep[2*l]   = (const float*)d_in[base+3];
    Wp[2*l+1]  = (const float*)d_in[base+4];
    gp[2*l+1]  = (const float*)d_in[base+6];
    bep[2*l+1] = (const float*)d_in[base+7];
  }

  size_t off = 0;
  char* base = (char*)d_ws;
  auto carve = [&](size_t bytes)->char* {
    char* q = base + off; off += (bytes + 255) & ~(size_t)255; return q;
  };
  // zero-init region: deg + total + 6 replicated stats buffers (contiguous)
  int* deg   = (int*)carve((size_t)NN*4);
  int* total = (int*)carve(4);
  float* stats[6];
  for (int i = 0; i < 6; ++i) stats[i] = (float*)carve((size_t)SREP*256*4);
  size_t zbytes = (size_t)(base + off - (char*)deg);   // multiple of 256

  int* row_off = (int*)carve((size_t)NN*4);
  int* cur     = (int*)carve((size_t)NN*4);
  int* col     = (int*)carve((size_t)(NE + 3*NN)*4);   // padded CSR
  unsigned short* wt[6];
  for (int i = 0; i < 6; ++i) wt[i] = (unsigned short*)carve(128*128*2);
  unsigned short* H0 = (unsigned short*)carve((size_t)(NN+1)*128*2);
  unsigned short* X  = (unsigned short*)carve((size_t)(NN+1)*128*2);
  unsigned short* Y1 = (unsigned short*)carve((size_t)(NN+1)*128*2);
  unsigned short* Y2 = (unsigned short*)carve((size_t)(NN+1)*128*2);

  // fast zero of deg+total+stats
  int zn4 = (int)(zbytes >> 4);
  k_zero<<<(zn4 + 255)/256, 256, 0, stream>>>((uint4v*)deg, zn4);

  W6 jb;
  for (int i = 0; i < 6; ++i){ jb.w[i] = Wp[i]; jb.o[i] = wt[i]; }
  k_pre<<<8898, 256, 0, stream>>>(features, H0, dst, deg, jb);
  k_offsets<<<(NN+255)/256, 256, 0, stream>>>(deg, row_off, cur, col, total);
  k_fill<<<(NE+255)/256, 256, 0, stream>>>(src, dst, cur, col, NE);

  const int agg_grid = 6250;           // 6250 blocks x 4 waves x 2 nodes = 50000
  const int g2_grid = (3125 + 7)/8;    // 391: CS=2, TM=4, 256 threads -> TPB=8
  const int g1_grid = (3125 + 15)/16;  // 196: CS=1, TM=4, 256 threads -> TPB=16

  // ---- layer 0 ----
  k_agg<false><<<agg_grid, 256, 0, stream>>>(H0, nullptr, nullptr, nullptr, row_off, deg, col, X);
  k_gemm<4,4,2,4,256,false><<<g2_grid, 256, 0, stream>>>(X, wt[0], nullptr, nullptr, nullptr, Y1, stats[0]);
  k_gemm<4,4,2,4,256,true ><<<g2_grid, 256, 0, stream>>>(Y1, wt[1], stats[0], gp[0], bep[0], Y2, stats[1]);
  // ---- layer 1 ----
  k_agg<true ><<<agg_grid, 256, 0, stream>>>(Y2, stats[1], gp[1], bep[1], row_off, deg, col, X);
  k_gemm<4,4,2,4,256,false><<<g2_grid, 256, 0, stream>>>(X, wt[2], nullptr, nullptr, nullptr, Y1, stats[2]);
  k_gemm<4,4,2,4,256,true ><<<g2_grid, 256, 0, stream>>>(Y1, wt[3], stats[2], gp[2], bep[2], Y2, stats[3]);
  // ---- layer 2 ----
  k_agg<true ><<<agg_grid, 256, 0, stream>>>(Y2, stats[3], gp[3], bep[3], row_off, deg, col, X);
  k_gemm<4,4,1,4,256,false><<<g1_grid, 256, 0, stream>>>(X, wt[4], nullptr, nullptr, nullptr, Y1, stats[4]);
  k_gemm<2,4,1,4,256,true ><<<g1_grid, 256, 0, stream>>>(Y1, wt[5], stats[4], gp[4], bep[4], Y2, stats[5]);
  k_final<<<782, 256, 0, stream>>>(Y2, stats[5], gp[5], bep[5], (float*)d_out);
}